// Round 15
// baseline (8680.909 us; speedup 1.0000x reference)
//
#include <hip/hip_runtime.h>
#include <math.h>

#define DEVI __device__ __forceinline__

typedef unsigned short us8 __attribute__((ext_vector_type(8)));
typedef short bfv __attribute__((ext_vector_type(8)));
typedef float f32x4 __attribute__((ext_vector_type(4)));

DEVI float sigmf_(float x){ return 1.0f/(1.0f+expf(-x)); }
DEVI float dot4_(const float4 a, const float4 b){ return a.x*b.x + a.y*b.y + a.z*b.z + a.w*b.w; }
DEVI float wred64(float v){
#pragma unroll
  for (int m = 32; m; m >>= 1) v += __shfl_xor(v, m);
  return v;
}
DEVI float b2f(unsigned short u){ return __uint_as_float(((unsigned)u)<<16); }
DEVI unsigned short f2bf(float x){
  unsigned u = __float_as_uint(x);
  return (unsigned short)((u + 0x7FFFu + ((u>>16)&1u)) >> 16);
}
DEVI void f2bf2(float x, unsigned short& hi, unsigned short& lo){
  hi = f2bf(x);
  lo = f2bf(x - b2f(hi));
}
DEVI unsigned short f2bf_lo(float x, unsigned short hi){
  return f2bf(x - b2f(hi));
}

DEVI float dotg(const unsigned short* wb, const float4* xr, int i8, float acc){
  us8 w = ((const us8*)wb)[i8];
  float4 xa = xr[2*i8], xb = xr[2*i8+1];
  acc += b2f(w[0])*xa.x; acc += b2f(w[1])*xa.y; acc += b2f(w[2])*xa.z; acc += b2f(w[3])*xa.w;
  acc += b2f(w[4])*xb.x; acc += b2f(w[5])*xb.y; acc += b2f(w[6])*xb.z; acc += b2f(w[7])*xb.w;
  return acc;
}
DEVI float dotg(const float* wb, const float4* xr, int i8, float acc){
  float4 wa = ((const float4*)wb)[2*i8], wv = ((const float4*)wb)[2*i8+1];
  float4 xa = xr[2*i8], xb = xr[2*i8+1];
  acc += wa.x*xa.x; acc += wa.y*xa.y; acc += wa.z*xa.z; acc += wa.w*xa.w;
  acc += wv.x*xb.x; acc += wv.y*xb.y; acc += wv.z*xb.z; acc += wv.w*xb.w;
  return acc;
}
template<typename WT>
DEVI float kdot1024(const WT* wbase, const float4* xr){
  float a0=0,a1=0,a2=0,a3=0;
#pragma unroll 4
  for (int it = 0; it < 32; ++it){
    a0 = dotg(wbase, xr, it*4+0, a0);
    a1 = dotg(wbase, xr, it*4+1, a1);
    a2 = dotg(wbase, xr, it*4+2, a2);
    a3 = dotg(wbase, xr, it*4+3, a3);
  }
  return (a0+a1)+(a2+a3);
}

// ---------------- prologue utility kernels ----------------

__global__ void zero2_k(float* __restrict__ a, float* __restrict__ b, int n){
  int i = blockIdx.x*256 + threadIdx.x;
  if (i < n){ a[i] = 0.f; b[i] = 0.f; }
}

__global__ void gather_k(const float* __restrict__ emb, const int* __restrict__ topic,
                         const int* __restrict__ essay, const int* __restrict__ mems,
                         float* __restrict__ xtop, float* __restrict__ embs,
                         float* __restrict__ Mraw,
                         unsigned short* __restrict__ Mhi, unsigned short* __restrict__ Mlo)
{
  int r = blockIdx.x, tid = threadIdx.x;
  int idx; float* dst; size_t boff = 0; bool wb = false;
  if (r < 128){ int tt = r>>4, b = r&15; idx = topic[b*8+tt]; dst = xtop + (size_t)r*512; }
  else if (r < 1168){ int rr = r-128; int s = rr>>4, b = rr&15; int col = s < 64 ? s : 63;
                      idx = essay[b*64+col]; dst = embs + (size_t)rr*512; }
  else { int rr = r-1168; idx = mems[rr]; dst = Mraw + (size_t)rr*512;
         boff = (size_t)rr*512; wb = (Mhi != nullptr); }
  const float4* s4 = (const float4*)(emb + (size_t)idx*512);
  float4 v = s4[tid];
  ((float4*)dst)[tid] = v;
  if (wb){
    ushort4 h, l;
    f2bf2(v.x, h.x, l.x); f2bf2(v.y, h.y, l.y);
    f2bf2(v.z, h.z, l.z); f2bf2(v.w, h.w, l.w);
    ((ushort4*)(Mhi+boff))[tid] = h;
    ((ushort4*)(Mlo+boff))[tid] = l;
  }
}

// tier0/2: UcatI fp32 interleaved + Ws3T fp32
__global__ void pack_k(const float* __restrict__ U1, const float* __restrict__ U2,
                       const float* __restrict__ sharpW,
                       float* __restrict__ UcatI, float* __restrict__ Ws3T)
{
  int gid = blockIdx.x*256 + threadIdx.x;
  if (gid < 524288){
    int n = gid>>9, k = gid&511;
    UcatI[gid] = (n&1) ? U2[(size_t)(n>>1)*512+k] : U1[(size_t)(n>>1)*512+k];
  } else {
    int g2 = gid - 524288;
    int k = g2>>10, j = g2&1023;
    Ws3T[g2] = sharpW[(size_t)j*2048 + 1536 + k];
  }
}

__global__ void pack_u_hilo(const float* __restrict__ U1, const float* __restrict__ U2,
                            unsigned short* __restrict__ Uhi, unsigned short* __restrict__ Ulo)
{
  int gid = blockIdx.x*256 + threadIdx.x;
  int n = gid>>9, k = gid&511;
  float v = (n&1) ? U2[(size_t)(n>>1)*512+k] : U1[(size_t)(n>>1)*512+k];
  unsigned short h, l;
  f2bf2(v, h, l);
  Uhi[gid] = h; Ulo[gid] = l;
}

// tier3: Ws3 (sharp_W cols 1536..2047) row-major [1024 j][512 k] -> hi/lo
__global__ void pack_ws3b(const float* __restrict__ sharpW,
                          unsigned short* __restrict__ hi, unsigned short* __restrict__ lo)
{
  int gid = blockIdx.x*256 + threadIdx.x;   // 524288
  int j = gid>>9, k = gid&511;
  float v = sharpW[(size_t)j*2048 + 1536 + k];
  unsigned short h, l;
  f2bf2(v, h, l);
  hi[gid] = h; lo[gid] = l;
}

__global__ void conv_k(const float* __restrict__ src, unsigned short* __restrict__ dst, int n8){
  int i = blockIdx.x*256 + threadIdx.x;
  if (i >= n8) return;
  float4 a = ((const float4*)src)[2*i], b = ((const float4*)src)[2*i+1];
  us8 o;
  o[0]=f2bf(a.x); o[1]=f2bf(a.y); o[2]=f2bf(a.z); o[3]=f2bf(a.w);
  o[4]=f2bf(b.x); o[5]=f2bf(b.y); o[6]=f2bf(b.z); o[7]=f2bf(b.w);
  ((us8*)dst)[i] = o;
}

__global__ void conv2_k(const float* __restrict__ src,
                        unsigned short* __restrict__ hi, unsigned short* __restrict__ lo, int n8){
  int i = blockIdx.x*256 + threadIdx.x;
  if (i >= n8) return;
  float4 a = ((const float4*)src)[2*i], b = ((const float4*)src)[2*i+1];
  us8 oh, ol;
  oh[0]=f2bf(a.x); ol[0]=f2bf_lo(a.x, oh[0]);
  oh[1]=f2bf(a.y); ol[1]=f2bf_lo(a.y, oh[1]);
  oh[2]=f2bf(a.z); ol[2]=f2bf_lo(a.z, oh[2]);
  oh[3]=f2bf(a.w); ol[3]=f2bf_lo(a.w, oh[3]);
  oh[4]=f2bf(b.x); ol[4]=f2bf_lo(b.x, oh[4]);
  oh[5]=f2bf(b.y); ol[5]=f2bf_lo(b.y, oh[5]);
  oh[6]=f2bf(b.z); ol[6]=f2bf_lo(b.z, oh[6]);
  oh[7]=f2bf(b.w); ol[7]=f2bf_lo(b.w, oh[7]);
  ((us8*)hi)[i] = oh;
  ((us8*)lo)[i] = ol;
}

// ---------------- generic fp32 tiled GEMM (prologue only) ----------------
template<int ACT>
__global__ void gemm_nt(const float* __restrict__ A, int lda,
                        const float* __restrict__ W, int ldw, int woff,
                        const float* __restrict__ bias,
                        float* __restrict__ C, int ldc, int M, int N, int K)
{
  __shared__ float As[1024], Ws[1024];
  const int bm = blockIdx.y*64, bn = blockIdx.x*64;
  const int tid = threadIdx.x;
  const int lr = tid>>2, lk = (tid&3)<<2;
  const int tm = (tid>>4)<<2, tn = (tid&15)<<2;
  float acc[4][4] = {};
  for (int k0 = 0; k0 < K; k0 += 16){
    float4 av = make_float4(0.f,0.f,0.f,0.f);
    if (bm+lr < M) av = *(const float4*)(A + (size_t)(bm+lr)*lda + k0 + lk);
    As[(lk+0)*64+lr]=av.x; As[(lk+1)*64+lr]=av.y; As[(lk+2)*64+lr]=av.z; As[(lk+3)*64+lr]=av.w;
    float4 wv = make_float4(0.f,0.f,0.f,0.f);
    if (bn+lr < N) wv = *(const float4*)(W + (size_t)(bn+lr)*ldw + woff + k0 + lk);
    Ws[(lk+0)*64+lr]=wv.x; Ws[(lk+1)*64+lr]=wv.y; Ws[(lk+2)*64+lr]=wv.z; Ws[(lk+3)*64+lr]=wv.w;
    __syncthreads();
#pragma unroll
    for (int k = 0; k < 16; ++k){
      float4 a = *(const float4*)&As[k*64+tm];
      float4 w = *(const float4*)&Ws[k*64+tn];
      acc[0][0]+=a.x*w.x; acc[0][1]+=a.x*w.y; acc[0][2]+=a.x*w.z; acc[0][3]+=a.x*w.w;
      acc[1][0]+=a.y*w.x; acc[1][1]+=a.y*w.y; acc[1][2]+=a.y*w.z; acc[1][3]+=a.y*w.w;
      acc[2][0]+=a.z*w.x; acc[2][1]+=a.z*w.y; acc[2][2]+=a.z*w.z; acc[2][3]+=a.z*w.w;
      acc[3][0]+=a.w*w.x; acc[3][1]+=a.w*w.y; acc[3][2]+=a.w*w.z; acc[3][3]+=a.w*w.w;
    }
    __syncthreads();
  }
#pragma unroll
  for (int i = 0; i < 4; ++i){
    int m = bm+tm+i; if (m >= M) continue;
#pragma unroll
    for (int j = 0; j < 4; ++j){
      int n = bn+tn+j; if (n >= N) continue;
      float v = acc[i][j] + (bias ? bias[n] : 0.f);
      if (ACT == 1) v = tanhf(v);
      C[(size_t)m*ldc + n] = v;
    }
  }
}

// ---------------- encoder LSTM step (fp32, 4 waves) ----------------
__global__ void enc_step(const float* __restrict__ xtop,
    const float* __restrict__ Wih_f, const float* __restrict__ Whh_f,
    const float* __restrict__ bih_f, const float* __restrict__ bhh_f,
    const float* __restrict__ Wih_b, const float* __restrict__ Whh_b,
    const float* __restrict__ bih_b, const float* __restrict__ bhh_b,
    const float* __restrict__ h_in, const float* __restrict__ c_in,
    float* __restrict__ h_out, float* __restrict__ c_out,
    float* __restrict__ topics, int t)
{
  const int dir = blockIdx.y;
  const int j = blockIdx.x*4 + (threadIdx.x>>6);
  const int lane = threadIdx.x & 63;
  const int b = lane & 15, g4 = lane >> 4;
  const int tt = dir ? (7 - t) : t;
  const float* Wih = dir ? Wih_b : Wih_f;
  const float* Whh = dir ? Whh_b : Whh_f;
  const float* bih = dir ? bih_b : bih_f;
  const float* bhh = dir ? bhh_b : bhh_f;
  const int row = g4*512 + j;
  float acc = bih[row] + bhh[row];
  const float4* wx = (const float4*)(Wih + (size_t)row*512);
  const float4* xv = (const float4*)(xtop + (size_t)(tt*16+b)*512);
#pragma unroll 8
  for (int k = 0; k < 128; ++k) acc += dot4_(wx[k], xv[k]);
  const float4* wh = (const float4*)(Whh + (size_t)row*512);
  const float4* hv = (const float4*)(h_in + (size_t)b*1024 + dir*512);
#pragma unroll 8
  for (int k = 0; k < 128; ++k) acc += dot4_(wh[k], hv[k]);
  float gi = __shfl(acc, b);
  float gf = __shfl(acc, b+16);
  float gg = __shfl(acc, b+32);
  float go = __shfl(acc, b+48);
  if (g4 == 0){
    float c_old = c_in[(size_t)b*1024 + dir*512 + j];
    float cn = sigmf_(gf)*c_old + sigmf_(gi)*tanhf(gg);
    float hn = sigmf_(go)*tanhf(cn);
    h_out[(size_t)b*1024 + dir*512 + j] = hn;
    c_out[(size_t)b*1024 + dir*512 + j] = cn;
    topics[(size_t)(b*8+tt)*1024 + dir*512 + j] = hn;
  }
}

// ---------------- memory-update GEMM, tier0/2 fp32 ----------------
DEVI void mem_gemm_role(int bid, const float* __restrict__ Min, float* __restrict__ Mout,
                        const float* __restrict__ U,
                        const float* __restrict__ eV1s, const float* __restrict__ eV2s,
                        float* lds, int tid)
{
  const int bm = (bid>>4)*64, bn = (bid&15)*64;
  float* As = lds; float* Ws = lds + 1024;
  const int lr = tid>>2, lk = (tid&3)<<2;
  const int tm = (tid>>4)<<2, tn = (tid&15)<<2;
  float acc[4][4] = {};
  for (int k0 = 0; k0 < 512; k0 += 16){
    float4 av = *(const float4*)(Min + (size_t)(bm+lr)*512 + k0 + lk);
    As[(lk+0)*64+lr]=av.x; As[(lk+1)*64+lr]=av.y; As[(lk+2)*64+lr]=av.z; As[(lk+3)*64+lr]=av.w;
    float4 wv = *(const float4*)(U + (size_t)(bn+lr)*512 + k0 + lk);
    Ws[(lk+0)*64+lr]=wv.x; Ws[(lk+1)*64+lr]=wv.y; Ws[(lk+2)*64+lr]=wv.z; Ws[(lk+3)*64+lr]=wv.w;
    __syncthreads();
#pragma unroll
    for (int k = 0; k < 16; ++k){
      float4 a = *(const float4*)&As[k*64+tm];
      float4 w = *(const float4*)&Ws[k*64+tn];
      acc[0][0]+=a.x*w.x; acc[0][1]+=a.x*w.y; acc[0][2]+=a.x*w.z; acc[0][3]+=a.x*w.w;
      acc[1][0]+=a.y*w.x; acc[1][1]+=a.y*w.y; acc[1][2]+=a.y*w.z; acc[1][3]+=a.y*w.w;
      acc[2][0]+=a.z*w.x; acc[2][1]+=a.z*w.y; acc[2][2]+=a.z*w.z; acc[2][3]+=a.z*w.w;
      acc[3][0]+=a.w*w.x; acc[3][1]+=a.w*w.y; acc[3][2]+=a.w*w.z; acc[3][3]+=a.w*w.w;
    }
    __syncthreads();
  }
  const int e0 = (bn+tn)>>1;
#pragma unroll
  for (int i = 0; i < 4; ++i){
    int r = bm+tm+i;
    int b = r/100;
#pragma unroll
    for (int p = 0; p < 2; ++p){
      int e = e0 + p;
      float oldv = Min[(size_t)r*512 + e];
      float mt = tanhf (acc[i][2*p]   + eV1s[(size_t)b*512 + e]);
      float g  = sigmf_(acc[i][2*p+1] + eV2s[(size_t)b*512 + e]);
      float mn = g*mt + (1.f-g)*oldv;
      if (!isfinite(mn)) mn = 1e-31f;
      Mout[(size_t)r*512 + e] = mn;
    }
  }
}

__global__ void mem_update_k(const float* __restrict__ Min, float* __restrict__ Mout,
                             const float* __restrict__ U,
                             const float* __restrict__ eV1s, const float* __restrict__ eV2s)
{
  __shared__ float lds[2080];
  mem_gemm_role(blockIdx.x, Min, Mout, U, eV1s, eV2s, lds, threadIdx.x);
}

// ---------------- memory-update GEMM, tier3: bf16 hi/lo MFMA ----------------
DEVI void mem_ep(f32x4 v, int m0, int n0, int i, int j, int kg, int r16, int lane,
                 const float* __restrict__ Min,
                 const float* __restrict__ eV1s, const float* __restrict__ eV2s,
                 float* __restrict__ Mout,
                 unsigned short* __restrict__ Mohi, unsigned short* __restrict__ Molo)
{
#pragma unroll
  for (int q = 0; q < 4; ++q){
    float val = v[q];
    float oth = __shfl_xor(val, 1);
    if (!(lane&1)){
      int m = m0 + i*16 + kg*4 + q;
      int n = n0 + j*16 + r16;
      int e = n>>1, bb = m/100;
      float mold = Min[(size_t)m*512 + e];
      float mt = tanhf (val + eV1s[(size_t)bb*512 + e]);
      float g  = sigmf_(oth + eV2s[(size_t)bb*512 + e]);
      float mn = g*mt + (1.f-g)*mold;
      if (!isfinite(mn)) mn = 1e-31f;
      Mout[(size_t)m*512 + e] = mn;
      unsigned short h, l;
      f2bf2(mn, h, l);
      Mohi[(size_t)m*512 + e] = h;
      Molo[(size_t)m*512 + e] = l;
    }
  }
}

// 1600 blocks, 32x32 tile/block, 4 waves split K, LDS reduce. XCD m-chunk swizzle inside.
DEVI void mem_mfma_role2(int hwbid, const float* __restrict__ Min,
                        const unsigned short* __restrict__ Mhi, const unsigned short* __restrict__ Mlo,
                        float* __restrict__ Mout,
                        unsigned short* __restrict__ Mohi, unsigned short* __restrict__ Molo,
                        const unsigned short* __restrict__ Uhi, const unsigned short* __restrict__ Ulo,
                        const float* __restrict__ eV1s, const float* __restrict__ eV2s,
                        int tid, float* __restrict__ lds)
{
  const int bid2 = (hwbid & 7)*200 + (hwbid >> 3);
  const int bm = (bid2 >> 5)*32, bn = (bid2 & 31)*32;
  const int wave = tid>>6, lane = tid&63;
  const int r16 = lane&15, kg = lane>>4;
  const size_t aoff = (size_t)(bm + r16)*512 + wave*128 + kg*8;
  const size_t boff = (size_t)(bn + r16)*512 + wave*128 + kg*8;
  const unsigned short* pa0h = Mhi + aoff; const unsigned short* pa0l = Mlo + aoff;
  const unsigned short* pb0h = Uhi + boff; const unsigned short* pb0l = Ulo + boff;
  f32x4 c00 = {}, c01 = {}, c10 = {}, c11 = {};
#pragma unroll
  for (int k0 = 0; k0 < 128; k0 += 32){
    bfv a0h = *(const bfv*)(pa0h + k0);
    bfv a0l = *(const bfv*)(pa0l + k0);
    bfv a1h = *(const bfv*)(pa0h + 16*512 + k0);
    bfv a1l = *(const bfv*)(pa0l + 16*512 + k0);
    bfv b0h = *(const bfv*)(pb0h + k0);
    bfv b0l = *(const bfv*)(pb0l + k0);
    bfv b1h = *(const bfv*)(pb0h + 16*512 + k0);
    bfv b1l = *(const bfv*)(pb0l + 16*512 + k0);
    c00 = __builtin_amdgcn_mfma_f32_16x16x32_bf16(a0h, b0h, c00, 0, 0, 0);
    c00 = __builtin_amdgcn_mfma_f32_16x16x32_bf16(a0h, b0l, c00, 0, 0, 0);
    c00 = __builtin_amdgcn_mfma_f32_16x16x32_bf16(a0l, b0h, c00, 0, 0, 0);
    c01 = __builtin_amdgcn_mfma_f32_16x16x32_bf16(a0h, b1h, c01, 0, 0, 0);
    c01 = __builtin_amdgcn_mfma_f32_16x16x32_bf16(a0h, b1l, c01, 0, 0, 0);
    c01 = __builtin_amdgcn_mfma_f32_16x16x32_bf16(a0l, b1h, c01, 0, 0, 0);
    c10 = __builtin_amdgcn_mfma_f32_16x16x32_bf16(a1h, b0h, c10, 0, 0, 0);
    c10 = __builtin_amdgcn_mfma_f32_16x16x32_bf16(a1h, b0l, c10, 0, 0, 0);
    c10 = __builtin_amdgcn_mfma_f32_16x16x32_bf16(a1l, b0h, c10, 0, 0, 0);
    c11 = __builtin_amdgcn_mfma_f32_16x16x32_bf16(a1h, b1h, c11, 0, 0, 0);
    c11 = __builtin_amdgcn_mfma_f32_16x16x32_bf16(a1h, b1l, c11, 0, 0, 0);
    c11 = __builtin_amdgcn_mfma_f32_16x16x32_bf16(a1l, b1h, c11, 0, 0, 0);
  }
  float* wbase = lds + wave*1024 + lane*4;
#pragma unroll
  for (int q = 0; q < 4; ++q){
    wbase[q]     = c00[q];
    wbase[256+q] = c01[q];
    wbase[512+q] = c10[q];
    wbase[768+q] = c11[q];
  }
  __syncthreads();
  f32x4 s;
#pragma unroll
  for (int q = 0; q < 4; ++q)
    s[q] = lds[       wave*256 + lane*4 + q] + lds[1024 + wave*256 + lane*4 + q]
         + lds[2048 + wave*256 + lane*4 + q] + lds[3072 + wave*256 + lane*4 + q];
  mem_ep(s, bm, bn, wave>>1, wave&1, kg, r16, lane, Min, eV1s, eV2s, Mout, Mohi, Molo);
}

__global__ __launch_bounds__(256,4) void mem_update_k2(
    const float* __restrict__ Min,
    const unsigned short* __restrict__ Mhi, const unsigned short* __restrict__ Mlo,
    float* __restrict__ Mout,
    unsigned short* __restrict__ Mohi, unsigned short* __restrict__ Molo,
    const unsigned short* __restrict__ Uhi, const unsigned short* __restrict__ Ulo,
    const float* __restrict__ eV1s, const float* __restrict__ eV2s)
{
  __shared__ float lds[4096];
  mem_mfma_role2(blockIdx.x, Min, Mhi, Mlo, Mout, Mohi, Molo, Uhi, Ulo, eV1s, eV2s, threadIdx.x, lds);
}

// ---------------- logits role (shared by attn_mega and logits_k) ----------------
DEVI void logits_role(int lb, int tid,
    const unsigned short* __restrict__ fcWb, const float* __restrict__ fcb,
    const unsigned short* __restrict__ hh, const unsigned short* __restrict__ hl,
    float* __restrict__ out, int t)
{
  const int wave = tid>>6, lane = tid&63;
  const int r16 = lane&15, kg = lane>>4;
  const int tile = lb*4 + wave;   // 0..1999
  const unsigned short* pa0 = fcWb + (size_t)(tile*16 + r16)*1024 + kg*8;
  const unsigned short* pbh = hh + (size_t)r16*1024 + kg*8;
  const unsigned short* pbl = hl + (size_t)r16*1024 + kg*8;
  f32x4 c0 = {};
#pragma unroll 4
  for (int k0 = 0; k0 < 1024; k0 += 32){
    bfv a0 = *(const bfv*)(pa0 + k0);
    bfv b0 = *(const bfv*)(pbh + k0);
    bfv b1 = *(const bfv*)(pbl + k0);
    c0 = __builtin_amdgcn_mfma_f32_16x16x32_bf16(a0, b0, c0, 0,0,0);
    c0 = __builtin_amdgcn_mfma_f32_16x16x32_bf16(a0, b1, c0, 0,0,0);
  }
  float* ob = out + (size_t)r16*2048000 + (size_t)t*32000;
#pragma unroll
  for (int q = 0; q < 4; ++q){
    int j0 = tile*16 + kg*4 + q;
    ob[j0] = c0[q] + fcb[j0];
  }
}

__global__ __launch_bounds__(256) void logits_k(
    const unsigned short* __restrict__ fcWb, const float* __restrict__ fcb,
    const unsigned short* __restrict__ hh, const unsigned short* __restrict__ hl,
    float* __restrict__ out, int t)
{
  logits_role(blockIdx.x, threadIdx.x, fcWb, fcb, hh, hl, out, t);
}

// ---------------- per-step kernel A, tier0/2 (fp32, includes xs) ----------------
__global__ void step_pre(const float* __restrict__ Min, float* __restrict__ Mout,
    const float* __restrict__ U,
    const float* __restrict__ eV1s, const float* __restrict__ eV2s,
    const float* __restrict__ qb, const float* __restrict__ vb,
    const float* __restrict__ pret, const float* __restrict__ tws2,
    const float* __restrict__ eWs1t, const float* __restrict__ sharp_b,
    const float* __restrict__ Ws3T, float* __restrict__ xs)
{
  __shared__ float lds[2080];
  const int tid = threadIdx.x;
  if (blockIdx.x >= 16){
    mem_gemm_role(blockIdx.x-16, Min, Mout, U, eV1s, eV2s, lds, tid);
    return;
  }
  const int b = blockIdx.x;
  lds[tid]         = qb[b*512 + tid];
  lds[tid+256]     = qb[b*512 + tid + 256];
  lds[512+tid]     = vb[b*512 + tid];
  lds[512+tid+256] = vb[b*512 + tid + 256];
  __syncthreads();
  {
    const int tq = tid>>5, l32 = tid&31;
    const float* pr = pret + (size_t)(b*8+tq)*512;
    float sv = 0.f;
#pragma unroll
    for (int i = 0; i < 16; ++i){ int a = l32 + 32*i; sv += pr[a]*lds[a]; }
#pragma unroll
    for (int m = 16; m; m >>= 1) sv += __shfl_xor(sv, m);
    if (l32 == 0) lds[1024+tq] = sv;
  }
  __syncthreads();
  {
    float mx = -1e30f;
#pragma unroll
    for (int i = 0; i < 8; ++i) mx = fmaxf(mx, lds[1024+i]);
    float sm = 0.f; float ev[8];
#pragma unroll
    for (int i = 0; i < 8; ++i){ ev[i] = expf(lds[1024+i]-mx); sm += ev[i]; }
    if (tid < 8) lds[1032+tid] = ev[tid]/sm;
  }
  __syncthreads();
  {
    const int wv = tid>>6, lane = tid&63;
    for (int l = wv; l < 100; l += 4){
      const float* Mr = Min + (size_t)(b*100+l)*512;
      float sv = 0.f;
#pragma unroll
      for (int i = 0; i < 8; ++i){ int k = lane + 64*i; sv += Mr[k]*lds[512+k]; }
      sv = wred64(sv);
      if (lane == 0) lds[1040+l] = sv;
    }
  }
  __syncthreads();
  float mx = -1e30f;
  for (int i = 0; i < 100; ++i) mx = fmaxf(mx, lds[1040+i]);
  __syncthreads();
  if (tid < 100) lds[1040+tid] = expf(lds[1040+tid]-mx);
  __syncthreads();
  float sm = 0.f;
  for (int i = 0; i < 100; ++i) sm += lds[1040+i];
  const float inv = 1.f/sm;
  for (int e = tid; e < 512; e += 256){
    float a = 0.f;
    for (int l = 0; l < 100; ++l) a += lds[1040+l]*Min[(size_t)(b*100+l)*512 + e];
    lds[1152+e] = a*inv;
  }
  __syncthreads();
  float a0[4];
#pragma unroll
  for (int r2 = 0; r2 < 4; ++r2){
    int j = tid + 256*r2;
    float v = sharp_b[j] + eWs1t[(size_t)b*1024 + j];
#pragma unroll
    for (int t2 = 0; t2 < 8; ++t2) v += lds[1032+t2]*tws2[(size_t)(b*8+t2)*1024 + j];
    a0[r2] = v;
  }
  for (int k = 0; k < 512; ++k){
    float mk = lds[1152+k];
    const float* wr = Ws3T + (size_t)k*1024;
    a0[0] += mk*wr[tid];
    a0[1] += mk*wr[tid+256];
    a0[2] += mk*wr[tid+512];
    a0[3] += mk*wr[tid+768];
  }
#pragma unroll
  for (int r2 = 0; r2 < 4; ++r2) xs[(size_t)b*1024 + tid + 256*r2] = a0[r2];
}

// ---------------- per-step mega kernel, tier3: mt (128) + logits(t-1) (nLog) + mem GEMM (1600) ----------------
__global__ __launch_bounds__(256,4) void attn_mega(
    const float* __restrict__ Min,
    const unsigned short* __restrict__ Mhi, const unsigned short* __restrict__ Mlo,
    float* __restrict__ Mout,
    unsigned short* __restrict__ Mohi, unsigned short* __restrict__ Molo,
    const unsigned short* __restrict__ Uhi, const unsigned short* __restrict__ Ulo,
    const float* __restrict__ eV1s, const float* __restrict__ eV2s,
    const float* __restrict__ qb, const float* __restrict__ vb,
    const float* __restrict__ pret,
    float* __restrict__ alphab,
    unsigned short* __restrict__ mthi, unsigned short* __restrict__ mtlo,
    const unsigned short* __restrict__ fcWb, const float* __restrict__ fcb,
    const unsigned short* __restrict__ hph, const unsigned short* __restrict__ hpl,
    float* __restrict__ out, int tlog, int nLog)
{
  __shared__ float lds[4096];
  const int tid = threadIdx.x;
  if (blockIdx.x >= 128){
    const int bid = blockIdx.x - 128;
    if (bid < nLog){
      logits_role(bid, tid, fcWb, fcb, hph, hpl, out, tlog);
      return;
    }
    mem_mfma_role2(bid - nLog, Min, Mhi, Mlo, Mout, Mohi, Molo, Uhi, Ulo, eV1s, eV2s, tid, lds);
    return;
  }
  const int b = blockIdx.x >> 3, ec = blockIdx.x & 7;
  lds[tid]         = qb[b*512 + tid];
  lds[tid+256]     = qb[b*512 + tid + 256];
  lds[512+tid]     = vb[b*512 + tid];
  lds[512+tid+256] = vb[b*512 + tid + 256];
  __syncthreads();
  // topic scores + softmax-8 + alpha (ec==0 blocks only)
  if (ec == 0){
    {
      const int tq = tid>>5, l32 = tid&31;
      const float* pr = pret + (size_t)(b*8+tq)*512;
      float sv = 0.f;
#pragma unroll
      for (int i = 0; i < 16; ++i){ int a = l32 + 32*i; sv += pr[a]*lds[a]; }
#pragma unroll
      for (int m = 16; m; m >>= 1) sv += __shfl_xor(sv, m);
      if (l32 == 0) lds[1024+tq] = sv;
    }
    __syncthreads();
    {
      float mx = -1e30f;
#pragma unroll
      for (int i = 0; i < 8; ++i) mx = fmaxf(mx, lds[1024+i]);
      float sm = 0.f; float ev[8];
#pragma unroll
      for (int i = 0; i < 8; ++i){ ev[i] = expf(lds[1024+i]-mx); sm += ev[i]; }
      if (tid < 8) alphab[b*8+tid] = ev[tid]/sm;
    }
    __syncthreads();
  }
  // memory scores (100)
  {
    const int wv = tid>>6, lane = tid&63;
    for (int l = wv; l < 100; l += 4){
      const float* Mr = Min + (size_t)(b*100+l)*512;
      float sv = 0.f;
#pragma unroll
      for (int i = 0; i < 8; ++i){ int k = lane + 64*i; sv += Mr[k]*lds[512+k]; }
      sv = wred64(sv);
      if (lane == 0) lds[1040+l] = sv;
    }
  }
  __syncthreads();
  // parallel softmax over 100 -> normalized weights in LDS
  {
    const int wv = tid>>6;
    float v100 = (tid < 100) ? lds[1040+tid] : -1e30f;
    float m1 = v100;
#pragma unroll
    for (int m = 32; m; m >>= 1) m1 = fmaxf(m1, __shfl_xor(m1, m));
    if ((tid&63) == 0) lds[1664+wv] = m1;
    __syncthreads();
    float mx = fmaxf(fmaxf(lds[1664], lds[1665]), fmaxf(lds[1666], lds[1667]));
    float e = (tid < 100) ? expf(v100 - mx) : 0.f;
    float s1 = e;
#pragma unroll
    for (int m = 32; m; m >>= 1) s1 += __shfl_xor(s1, m);
    if ((tid&63) == 0) lds[1668+wv] = s1;
    __syncthreads();
    float sm = lds[1668]+lds[1669]+lds[1670]+lds[1671];
    if (tid < 100) lds[1800+tid] = e/sm;
  }
  __syncthreads();
  // m_t for e-chunk ec
  {
    const int e = ec*64 + (tid & 63);
    const int lg = tid >> 6;
    float a = 0.f;
    for (int l = lg*25; l < lg*25 + 25; ++l)
      a += lds[1800+l] * Min[(size_t)(b*100 + l)*512 + e];
    lds[1904 + lg*64 + (tid & 63)] = a;
    __syncthreads();
    if (lg == 0){
      float s = lds[1904 + tid] + lds[1968 + tid] + lds[2032 + tid] + lds[2096 + tid];
      unsigned short h, l2;
      f2bf2(s, h, l2);
      mthi[b*512 + e] = h;
      mtlo[b*512 + e] = l2;
    }
  }
}

// ---------------- per-step kernel A2, tier3: xs via hi/lo MFMA (64 blocks) ----------------
__global__ __launch_bounds__(256) void xs_k(
    const unsigned short* __restrict__ Ws3hi, const unsigned short* __restrict__ Ws3lo,
    const unsigned short* __restrict__ mthi, const unsigned short* __restrict__ mtlo,
    const float* __restrict__ alphab, const float* __restrict__ sharp_b,
    const float* __restrict__ eWs1t, const float* __restrict__ tws2,
    unsigned short* __restrict__ xshi, unsigned short* __restrict__ xslo)
{
  __shared__ float lds[1024];
  const int tid = threadIdx.x, wave = tid>>6, lane = tid&63;
  const int r16 = lane&15, kg = lane>>4;
  const int jt = blockIdx.x;    // 0..63
  const size_t aoff = (size_t)(jt*16 + r16)*512 + wave*128 + kg*8;
  const size_t boff = (size_t)r16*512 + wave*128 + kg*8;
  f32x4 c0 = {};
#pragma unroll
  for (int k0 = 0; k0 < 128; k0 += 32){
    bfv ah = *(const bfv*)(Ws3hi + aoff + k0);
    bfv al = *(const bfv*)(Ws3lo + aoff + k0);
    bfv bh = *(const bfv*)(mthi + boff + k0);
    bfv bl = *(const bfv*)(mtlo + boff + k0);
    c0 = __builtin_amdgcn_mfma_f32_16x16x32_bf16(ah, bh, c0, 0,0,0);
    c0 = __builtin_amdgcn_mfma_f32_16x16x32_bf16(ah, bl, c0, 0,0,0);
    c0 = __builtin_amdgcn_mfma_f32_16x16x32_bf16(al, bh, c0, 0,0,0);
  }
  float* wb2 = lds + wave*256 + lane*4;
#pragma unroll
  for (int q = 0; q < 4; ++q) wb2[q] = c0[q];
  __syncthreads();
  if (wave == 0){
    const int b = r16;
#pragma unroll
    for (int q = 0; q < 4; ++q){
      float s = lds[lane*4+q] + lds[256+lane*4+q] + lds[512+lane*4+q] + lds[768+lane*4+q];
      int j = jt*16 + kg*4 + q;
      float v2 = s + sharp_b[j] + eWs1t[(size_t)b*1024 + j];
#pragma unroll
      for (int t2 = 0; t2 < 8; ++t2) v2 += alphab[b*8+t2]*tws2[(size_t)(b*8+t2)*1024 + j];
      unsigned short h, l;
      f2bf2(v2, h, l);
      xshi[b*1024+j] = h;
      xslo[b*1024+j] = l;
    }
  }
}

// ---------------- per-step kernel B, tier0/2 ----------------
__global__ void dec_lstm(const float* __restrict__ xs,
    const float* __restrict__ Wih, const float* __restrict__ Whh,
    const float* __restrict__ bih, const float* __restrict__ bhh,
    const float* __restrict__ h_in, const float* __restrict__ c_in,
    float* __restrict__ h_out, float* __restrict__ c_out)
{
  const int j = blockIdx.x*4 + (threadIdx.x>>6);
  const int lane = threadIdx.x & 63;
  const int b = lane & 15, g4 = lane >> 4;
  const int row = g4*1024 + j;
  float acc = bih[row] + bhh[row];
  const float4* w1 = (const float4*)(Wih + (size_t)row*1024);
  const float4* x1 = (const float4*)(xs + (size_t)b*1024);
#pragma unroll 8
  for (int k = 0; k < 256; ++k) acc += dot4_(w1[k], x1[k]);
  const float4* w2 = (const float4*)(Whh + (size_t)row*1024);
  const float4* h1 = (const float4*)(h_in + (size_t)b*1024);
#pragma unroll 8
  for (int k = 0; k < 256; ++k) acc += dot4_(w2[k], h1[k]);
  float gi = __shfl(acc, b);
  float gf = __shfl(acc, b+16);
  float gg = __shfl(acc, b+32);
  float go = __shfl(acc, b+48);
  if (g4 == 0){
    float c_old = c_in[(size_t)b*1024 + j];
    float cn = sigmf_(gf)*c_old + sigmf_(gi)*tanhf(gg);
    float hn = sigmf_(go)*tanhf(cn);
    h_out[(size_t)b*1024 + j] = hn;
    c_out[(size_t)b*1024 + j] = cn;
  }
}

// ---------------- per-step kernel B, tier3: MFMA decoder LSTM, 256 blocks (R7-proven) ----------------
// block = (jt 0..63)*4 + gate. 4 waves = K-chunks of 256. Partial gate sums -> pgat;
// last-arriving block of each jt does the cell update (device-scope atomic counter).
// Summation order over kh identical to the 64-block LDS reduce -> bit-identical.
__global__ __launch_bounds__(256) void dec_mfma2(
    const unsigned short* __restrict__ xsh, const unsigned short* __restrict__ xsl,
    const unsigned short* __restrict__ Wih_h, const unsigned short* __restrict__ Wih_l,
    const unsigned short* __restrict__ Whh_h, const unsigned short* __restrict__ Whh_l,
    const float* __restrict__ bih, const float* __restrict__ bhh,
    const unsigned short* __restrict__ hih, const unsigned short* __restrict__ hil,
    const float* __restrict__ c_in,
    float* __restrict__ h_out, float* __restrict__ c_out,
    unsigned short* __restrict__ hoh, unsigned short* __restrict__ hol,
    unsigned short* __restrict__ coh, unsigned short* __restrict__ col_,
    float* __restrict__ pgat, int* __restrict__ cnt)
{
  __shared__ int winflag;
  const int tid = threadIdx.x, kh = tid>>6, lane = tid&63;
  const int r16 = lane&15, kg = lane>>4;
  const int jt = blockIdx.x>>2, g = blockIdx.x&3;
  const size_t arow = (size_t)(jt*16 + r16)*1024 + kh*256 + kg*8 + (size_t)g*1048576;
  const size_t boff = (size_t)r16*1024 + kh*256 + kg*8;
  f32x4 cc = {};
#pragma unroll 2
  for (int k0 = 0; k0 < 256; k0 += 32){
    bfv bxh = *(const bfv*)(xsh + boff + k0);
    bfv bxl = *(const bfv*)(xsl + boff + k0);
    bfv bhh_ = *(const bfv*)(hih + boff + k0);
    bfv bhl_ = *(const bfv*)(hil + boff + k0);
    bfv aih = *(const bfv*)(Wih_h + arow + k0);
    bfv ail = *(const bfv*)(Wih_l + arow + k0);
    bfv ahh = *(const bfv*)(Whh_h + arow + k0);
    bfv ahl = *(const bfv*)(Whh_l + arow + k0);
    cc = __builtin_amdgcn_mfma_f32_16x16x32_bf16(aih, bxh, cc, 0,0,0);
    cc = __builtin_amdgcn_mfma_f32_16x16x32_bf16(aih, bxl, cc, 0,0,0);
    cc = __builtin_amdgcn_mfma_f32_16x16x32_bf16(ail, bxh, cc, 0,0,0);
    cc = __builtin_amdgcn_mfma_f32_16x16x32_bf16(ahh, bhh_, cc, 0,0,0);
    cc = __builtin_amdgcn_mfma_f32_16x16x32_bf16(ahh, bhl_, cc, 0,0,0);
    cc = __builtin_amdgcn_mfma_f32_16x16x32_bf16(ahl, bhh_, cc, 0,0,0);
  }
  // store partials: pgat[jt][g][kh][joff][b], joff = kg*4+q, b = r16
  float* pg = pgat + ((((size_t)jt*4 + g)*4 + kh)*256);
#pragma unroll
  for (int q = 0; q < 4; ++q) pg[(kg*4+q)*16 + r16] = cc[q];
  __threadfence();
  __syncthreads();
  if (tid == 0){
    int old = atomicAdd(cnt + jt, 1);
    winflag = (old == 3) ? 1 : 0;
  }
  __syncthreads();
  if (winflag){
    __threadfence();
    const int b = tid&15, joff = tid>>4;
    const int j = jt*16 + joff;
    const float* pj = pgat + (size_t)jt*4096;
    float gv[4];
#pragma unroll
    for (int g2 = 0; g2 < 4; ++g2){
      gv[g2] = pj[(g2*4+0)*256 + joff*16 + b] + pj[(g2*4+1)*256 + joff*16 + b]
             + pj[(g2*4+2)*256 + joff*16 + b] + pj[(g2*4+3)*256 + joff*16 + b];
    }
    float gi = gv[0] + bih[j]        + bhh[j];
    float gf = gv[1] + bih[1024+j]   + bhh[1024+j];
    float gg = gv[2] + bih[2048+j]   + bhh[2048+j];
    float go = gv[3] + bih[3072+j]   + bhh[3072+j];
    float cold = c_in[b*1024 + j];
    float cn = sigmf_(gf)*cold + sigmf_(gi)*tanhf(gg);
    float hn = sigmf_(go)*tanhf(cn);
    h_out[b*1024 + j] = hn;
    c_out[b*1024 + j] = cn;
    unsigned short uh, ul;
    f2bf2(hn, uh, ul); hoh[b*1024+j] = uh; hol[b*1024+j] = ul;
    f2bf2(cn, uh, ul); coh[b*1024+j] = uh; col_[b*1024+j] = ul;
    if (tid == 0) cnt[jt] = 0;   // self-reset for next step / graph replay
  }
}

// ---------------- per-step kernel qv, tier3: q and v (64 blocks, K-split 4 + LDS reduce) ----------------
__global__ __launch_bounds__(256) void qv_k(
    const unsigned short* __restrict__ W2h, const unsigned short* __restrict__ W2l,
    const unsigned short* __restrict__ mWh, const unsigned short* __restrict__ mWl,
    const float* __restrict__ memb,
    const unsigned short* __restrict__ hh, const unsigned short* __restrict__ hl,
    const unsigned short* __restrict__ ch, const unsigned short* __restrict__ cl,
    float* __restrict__ qb, float* __restrict__ vb)
{
  __shared__ float lds[1024];
  const int tid = threadIdx.x, wave = tid>>6, lane = tid&63;
  const int r16 = lane&15, kg = lane>>4;
  const bool isV = blockIdx.x >= 32;
  const int tile = isV ? ((int)blockIdx.x - 32) : (int)blockIdx.x;   // 0..31
  const unsigned short* Ah = isV ? mWh : W2h;
  const unsigned short* Al = isV ? mWl : W2l;
  const unsigned short* Bh = isV ? hh : ch;
  const unsigned short* Bl = isV ? hl : cl;
  const size_t aoff = (size_t)(tile*16 + r16)*1024 + wave*256 + kg*8;
  const size_t boff = (size_t)r16*1024 + wave*256 + kg*8;
  f32x4 c0 = {};
#pragma unroll
  for (int k0 = 0; k0 < 256; k0 += 32){
    bfv ah = *(const bfv*)(Ah + aoff + k0);
    bfv al = *(const bfv*)(Al + aoff + k0);
    bfv b0 = *(const bfv*)(Bh + boff + k0);
    bfv b1 = *(const bfv*)(Bl + boff + k0);
    c0 = __builtin_amdgcn_mfma_f32_16x16x32_bf16(ah, b0, c0, 0,0,0);
    c0 = __builtin_amdgcn_mfma_f32_16x16x32_bf16(ah, b1, c0, 0,0,0);
    c0 = __builtin_amdgcn_mfma_f32_16x16x32_bf16(al, b0, c0, 0,0,0);
  }
  float* wb2 = lds + wave*256 + lane*4;
#pragma unroll
  for (int q = 0; q < 4; ++q) wb2[q] = c0[q];
  __syncthreads();
  if (wave == 0){
#pragma unroll
    for (int q = 0; q < 4; ++q){
      float s = lds[lane*4+q] + lds[256+lane*4+q] + lds[512+lane*4+q] + lds[768+lane*4+q];
      int j = tile*16 + kg*4 + q;
      if (isV) vb[r16*512 + j] = tanhf(s + memb[j]);
      else     qb[r16*512 + j] = s;
    }
  }
}

// ---------------- per-step kernel C, tier0/2 ----------------
template<typename WT>
__global__ __launch_bounds__(256,4) void step_out_t(const float* __restrict__ h, const float* __restrict__ c,
    const WT* __restrict__ fcW_, const float* __restrict__ fcb,
    const float* __restrict__ W2, const float* __restrict__ memW,
    const float* __restrict__ memb,
    float* __restrict__ out, float* __restrict__ qb, float* __restrict__ vb, int t)
{
  __shared__ float tile[256];
  const int bid = blockIdx.x;
  const int wv = threadIdx.x>>6, lane = threadIdx.x&63;
  const int b = lane&15, jj = lane>>4;
  if (bid < 2000){
    const int j = bid*16 + wv*4 + jj;
    float acc = kdot1024(fcW_ + (size_t)j*1024, (const float4*)(h + (size_t)b*1024));
    tile[(wv*4+jj)*16 + b] = acc;
    __syncthreads();
    const int b2 = threadIdx.x>>4, j2 = threadIdx.x&15;
    out[(size_t)b2*2048000 + (size_t)t*32000 + bid*16 + j2] = tile[j2*16+b2] + fcb[bid*16+j2];
  } else if (bid < 2032){
    const int j = (bid-2000)*16 + wv*4 + jj;
    float acc = kdot1024(W2 + (size_t)j*1024, (const float4*)(c + (size_t)b*1024));
    qb[b*512 + j] = acc;
  } else {
    const int j = (bid-2032)*16 + wv*4 + jj;
    float acc = kdot1024(memW + (size_t)j*1024, (const float4*)(h + (size_t)b*1024));
    vb[b*512 + j] = tanhf(acc + memb[j]);
  }
}

// ---------------- host launch ----------------
extern "C" void kernel_launch(void* const* d_in, const int* in_sizes, int n_in,
                              void* d_out, int out_size, void* d_ws, size_t ws_size,
                              hipStream_t stream)
{
  const float* embedding = (const float*)d_in[0];
  const float* Wih_f = (const float*)d_in[1];
  const float* Whh_f = (const float*)d_in[2];
  const float* bih_f = (const float*)d_in[3];
  const float* bhh_f = (const float*)d_in[4];
  const float* Wih_b = (const float*)d_in[5];
  const float* Whh_b = (const float*)d_in[6];
  const float* bih_b = (const float*)d_in[7];
  const float* bhh_b = (const float*)d_in[8];
  const float* W1    = (const float*)d_in[9];
  const float* W2    = (const float*)d_in[10];
  const float* mem_W = (const float*)d_in[11];
  const float* mem_b = (const float*)d_in[12];
  const float* U1    = (const float*)d_in[13];
  const float* V1    = (const float*)d_in[14];
  const float* U2    = (const float*)d_in[15];
  const float* V2    = (const float*)d_in[16];
  const float* sharp_W = (const float*)d_in[17];
  const float* sharp_b = (const float*)d_in[18];
  const float* dec_Wih = (const float*)d_in[19];
  const float* dec_Whh = (const float*)d_in[20];
  const float* dec_bih = (const float*)d_in[21];
  const float* dec_bhh = (const float*)d_in[22];
  const float* fc_W  = (const float*)d_in[23];
  const float* fc_b  = (const float*)d_in[24];
  const int* topic   = (const int*)d_in[25];
  const int* essay   = (const int*)d_in[27];
  const int* mems    = (const int*)d_in[29];
  float* out = (float*)d_out;
  float* ws = (float*)d_ws;

  // fp32 region
  float* x_topic = ws;                 // [8][16][512]
  float* embs    = ws + 65536;         // [65][16][512]
  float* eV1     = ws + 598016;        // [65][16][512]
  float* eV2     = ws + 1130496;       // [65][16][512]
  float* eWs1    = ws + 1662976;       // [65][16][1024]
  float* topics  = ws + 2727936;       // [16][8][1024]
  float* tws2    = ws + 2859008;       // [16][8][1024]
  float* pret    = ws + 2990080;       // [16][8][512]
  float* Mb0     = ws + 3055616;       // [1600][512]
  float* Mb1     = ws + 3874816;       // [1600][512]
  float* h_buf   = ws + 4694016;       // [2][16][1024]
  float* c_buf   = ws + 4726784;       // [2][16][1024]
  float* xs      = ws + 4759552;       // [16][1024]
  float* qb      = ws + 4775936;       // [16][512]
  float* vb      = ws + 4784128;       // [16][512]
  float* UcatI   = ws + 4792320;       // [1024][512] fp32 (tier<3)
  float* Ws3T    = ws + 5316608;       // [512][1024] fp32 (tier<3)  end 5840896
  // tier3 aliases inside UcatI/Ws3T slots (mutually exclusive with tier<3 use)
  unsigned short* Ws3hi = (unsigned short*)(ws + 4792320);   // [1024][512] us
  unsigned short* Ws3lo = (unsigned short*)(ws + 5054464);   // [1024][512] us
  unsigned short* mthi  = (unsigned short*)(ws + 5316608);   // [16][512] us
  unsigned short* mtlo  = (unsigned short*)(ws + 5320704);   // [16][512] us
  float*          alphab= ws + 5324800;                      // [16][8] f
  float*          pgat  = ws + 5324928;                      // [64][4][4][16][16] f = 262144
  int*            cnt   = (int*)(ws + 5587072);              // [64] i, end 5587136 < 5840896
  // hi/lo region
  unsigned short* Uhi   = (unsigned short*)(ws + 5840896);
  unsigned short* Ulo   = (unsigned short*)(ws + 6103040);
  unsigned short* Mb0hi = (unsigned short*)(ws + 6365184);
  unsigned short* Mb0lo = (unsigned short*)(ws + 6774784);
  unsigned short* Mb1hi = (unsigned short*)(ws + 7184384);
  unsigned short* Mb1lo = (unsigned short*)(ws + 7593984);   // end 8003584 f
  unsigned short* fcWb  = (unsigned short*)(ws + 8003584);   // end 24387584 f
  // tier3 weights/state
  unsigned short* dWihHi = (unsigned short*)(ws + 24387584);
  unsigned short* dWihLo = (unsigned short*)(ws + 26484736);
  unsigned short* dWhhHi = (unsigned short*)(ws + 28581888);
  unsigned short* dWhhLo = (unsigned short*)(ws + 30679040);
  unsigned short* W2h    = (unsigned short*)(ws + 32776192);
  unsigned short* W2l    = (unsigned short*)(ws + 33038336);
  unsigned short* mWh    = (unsigned short*)(ws + 33300480);
  unsigned short* mWl    = (unsigned short*)(ws + 33562624);
  unsigned short* hbhi   = (unsigned short*)(ws + 33824768);
  unsigned short* hblo   = (unsigned short*)(ws + 33841152);
  unsigned short* cbhi   = (unsigned short*)(ws + 33857536);
  unsigned short* cblo   = (unsigned short*)(ws + 33873920);
  unsigned short* xshi   = (unsigned short*)(ws + 33890304);
  unsigned short* xslo   = (unsigned short*)(ws + 33898496); // end 33906688 f

  const size_t NEED2 = (size_t)24387584 * 4;
  const size_t NEED3 = (size_t)33906688 * 4;   // ~135.6 MB (unchanged)
  const int tier = (ws_size >= NEED3) ? 3 : (ws_size >= NEED2 ? 2 : 0);

  if (tier < 3){
    // -------- proven fp32 path; tier2 uses bf16 fc_W for logits --------
    zero2_k<<<64,256,0,stream>>>(h_buf, c_buf, 16384);
    gather_k<<<2768,128,0,stream>>>(embedding, topic, essay, mems, x_topic, embs, Mb1, nullptr, nullptr);
    pack_k<<<4096,256,0,stream>>>(U1, U2, sharp_W, UcatI, Ws3T);
    if (tier == 2) conv_k<<<16000,256,0,stream>>>(fc_W, fcWb, 4096000);
    gemm_nt<0><<<dim3(8,17),256,0,stream>>>(embs,512, V1,512,0, nullptr, eV1,512, 1040,512,512);
    gemm_nt<0><<<dim3(8,17),256,0,stream>>>(embs,512, V2,512,0, nullptr, eV2,512, 1040,512,512);
    gemm_nt<0><<<dim3(16,17),256,0,stream>>>(embs,512, sharp_W,2048,0, nullptr, eWs1,1024, 1040,1024,512);
    for (int t = 0; t < 8; ++t){
      const float* hi = h_buf + (t&1)*16384;
      const float* ci = c_buf + (t&1)*16384;
      float* ho = h_buf + ((t+1)&1)*16384;
      float* co = c_buf + ((t+1)&1)*16384;
      enc_step<<<dim3(128,2),256,0,stream>>>(x_topic, Wih_f,Whh_f,bih_f,bhh_f,
                                             Wih_b,Whh_b,bih_b,bhh_b, hi,ci,ho,co, topics, t);
    }
    gemm_nt<0><<<dim3(8,2),256,0,stream>>>(topics,1024, W1,1024,0, nullptr, pret,512, 128,512,1024);
    gemm_nt<0><<<dim3(16,2),256,0,stream>>>(topics,1024, sharp_W,2048,512, nullptr, tws2,1024, 128,1024,1024);
    gemm_nt<0><<<dim3(8,1),256,0,stream>>>(c_buf,1024, W2,1024,0, nullptr, qb,512, 16,512,1024);
    gemm_nt<1><<<dim3(8,1),256,0,stream>>>(h_buf,1024, mem_W,1024,0, mem_b, vb,512, 16,512,1024);
    mem_update_k<<<400,256,0,stream>>>(Mb1, Mb0, UcatI, eV1, eV2);
    for (int t = 0; t < 64; ++t){
      float* Mi = (t&1) ? Mb1 : Mb0;
      float* Mo = (t&1) ? Mb0 : Mb1;
      int nb = (t < 63) ? 416 : 16;
      step_pre<<<nb,256,0,stream>>>(Mi, Mo, UcatI,
          eV1 + (size_t)(t+1)*8192, eV2 + (size_t)(t+1)*8192,
          qb, vb, pret, tws2, eWs1 + (size_t)t*16384, sharp_b, Ws3T, xs);
      const float* hi = h_buf + (t&1)*16384;
      const float* ci = c_buf + (t&1)*16384;
      float* ho = h_buf + ((t+1)&1)*16384;
      float* co = c_buf + ((t+1)&1)*16384;
      dec_lstm<<<256,256,0,stream>>>(xs, dec_Wih, dec_Whh, dec_bih, dec_bhh, hi, ci, ho, co);
      if (tier == 2)
        step_out_t<unsigned short><<<2064,256,0,stream>>>(ho, co, fcWb, fc_b, W2, mem_W, mem_b, out, qb, vb, t);
      else
        step_out_t<float><<<2064,256,0,stream>>>(ho, co, fc_W, fc_b, W2, mem_W, mem_b, out, qb, vb, t);
    }
    return;
  }

  // -------- tier3 pipeline --------
  zero2_k<<<64,256,0,stream>>>(h_buf, c_buf, 16384);
  hipMemsetAsync(cnt, 0, 64*sizeof(int), stream);
  gather_k<<<2768,128,0,stream>>>(embedding, topic, essay, mems, x_topic, embs, Mb1, Mb1hi, Mb1lo);
  pack_u_hilo<<<2048,256,0,stream>>>(U1, U2, Uhi, Ulo);
  pack_ws3b<<<2048,256,0,stream>>>(sharp_W, Ws3hi, Ws3lo);
  conv_k<<<16000,256,0,stream>>>(fc_W, fcWb, 4096000);
  conv2_k<<<2048,256,0,stream>>>(dec_Wih, dWihHi, dWihLo, 524288);
  conv2_k<<<2048,256,0,stream>>>(dec_Whh, dWhhHi, dWhhLo, 524288);
  conv2_k<<<256,256,0,stream>>>(W2, W2h, W2l, 65536);
  conv2_k<<<256,256,0,stream>>>(mem_W, mWh, mWl, 65536);

  gemm_nt<0><<<dim3(8,17),256,0,stream>>>(embs,512, V1,512,0, nullptr, eV1,512, 1040,512,512);
  gemm_nt<0><<<dim3(8,17),256,0,stream>>>(embs,512, V2,512,0, nullptr, eV2,512, 1040,512,512);
  gemm_nt<0><<<dim3(16,17),256,0,stream>>>(embs,512, sharp_W,2048,0, nullptr, eWs1,1024, 1040,1024,512);

  for (int t = 0; t < 8; ++t){
    const float* hi = h_buf + (t&1)*16384;
    const float* ci = c_buf + (t&1)*16384;
    float* ho = h_buf + ((t+1)&1)*16384;
    float* co = c_buf + ((t+1)&1)*16384;
    enc_step<<<dim3(128,2),256,0,stream>>>(x_topic, Wih_f,Whh_f,bih_f,bhh_f,
                                           Wih_b,Whh_b,bih_b,bhh_b, hi,ci,ho,co, topics, t);
  }
  gemm_nt<0><<<dim3(8,2),256,0,stream>>>(topics,1024, W1,1024,0, nullptr, pret,512, 128,512,1024);
  gemm_nt<0><<<dim3(16,2),256,0,stream>>>(topics,1024, sharp_W,2048,512, nullptr, tws2,1024, 128,1024,1024);
  gemm_nt<0><<<dim3(8,1),256,0,stream>>>(c_buf,1024, W2,1024,0, nullptr, qb,512, 16,512,1024);
  gemm_nt<1><<<dim3(8,1),256,0,stream>>>(h_buf,1024, mem_W,1024,0, mem_b, vb,512, 16,512,1024);
  conv2_k<<<8,256,0,stream>>>(h_buf, hbhi, hblo, 2048);   // parity-0 initial state
  conv2_k<<<8,256,0,stream>>>(c_buf, cbhi, cblo, 2048);
  mem_update_k2<<<1600,256,0,stream>>>(Mb1, Mb1hi, Mb1lo, Mb0, Mb0hi, Mb0lo, Uhi, Ulo, eV1, eV2);

  for (int t = 0; t < 64; ++t){
    float* Mi = (t&1) ? Mb1 : Mb0;
    unsigned short* Mihi = (t&1) ? Mb1hi : Mb0hi;
    unsigned short* Milo = (t&1) ? Mb1lo : Mb0lo;
    float* Mo = (t&1) ? Mb0 : Mb1;
    unsigned short* Mohi = (t&1) ? Mb0hi : Mb1hi;
    unsigned short* Molo = (t&1) ? Mb0lo : Mb1lo;
    const int par = t&1, nxt = (t+1)&1;
    const int nLog = (t > 0) ? 500 : 0;
    const int nGemm = (t < 63) ? 1600 : 0;
    // mega-dispatch: mt(t) [128] + logits(t-1) [nLog] + mem GEMM M(t)->M(t+1) [nGemm]
    attn_mega<<<128 + nLog + nGemm,256,0,stream>>>(Mi, Mihi, Milo, Mo, Mohi, Molo, Uhi, Ulo,
        eV1 + (size_t)(t+1)*8192, eV2 + (size_t)(t+1)*8192,
        qb, vb, pret, alphab, mthi, mtlo,
        fcWb, fc_b, hbhi + par*16384, hblo + par*16384, out, t-1, nLog);
    xs_k<<<64,256,0,stream>>>(Ws3hi, Ws3lo, mthi, mtlo, alphab, sharp_b,
        eWs1 + (size_t)t*16384, tws2, xshi, xslo);
    const float* ci = c_buf + par*16384;
    float* ho = h_buf + nxt*16384;
    float* co = c_buf + nxt*16384;
    dec_mfma2<<<256,256,0,stream>>>(xshi, xslo, dWihHi, dWihLo, dWhhHi, dWhhLo,
        dec_bih, dec_bhh,
        hbhi + par*16384, hblo + par*16384, ci,
        ho, co,
        hbhi + nxt*16384, hblo + nxt*16384, cbhi + nxt*16384, cblo + nxt*16384,
        pgat, cnt);
    if (t < 63)
      qv_k<<<64,256,0,stream>>>(W2h, W2l, mWh, mWl, mem_b,
          hbhi + nxt*16384, hblo + nxt*16384, cbhi + nxt*16384, cblo + nxt*16384, qb, vb);
  }
  // final logits for t=63 (h-state parity 0 after dec(63))
  logits_k<<<500,256,0,stream>>>(fcWb, fc_b, hbhi, hblo, out, 63);
}

// Round 16
// 6807.059 us; speedup vs baseline: 1.2753x; 1.2753x over previous
//
#include <hip/hip_runtime.h>
#include <math.h>

#define DEVI __device__ __forceinline__

typedef unsigned short us8 __attribute__((ext_vector_type(8)));
typedef short bfv __attribute__((ext_vector_type(8)));
typedef float f32x4 __attribute__((ext_vector_type(4)));

DEVI float sigmf_(float x){ return 1.0f/(1.0f+expf(-x)); }
DEVI float dot4_(const float4 a, const float4 b){ return a.x*b.x + a.y*b.y + a.z*b.z + a.w*b.w; }
DEVI float wred64(float v){
#pragma unroll
  for (int m = 32; m; m >>= 1) v += __shfl_xor(v, m);
  return v;
}
DEVI float b2f(unsigned short u){ return __uint_as_float(((unsigned)u)<<16); }
DEVI unsigned short f2bf(float x){
  unsigned u = __float_as_uint(x);
  return (unsigned short)((u + 0x7FFFu + ((u>>16)&1u)) >> 16);
}
DEVI void f2bf2(float x, unsigned short& hi, unsigned short& lo){
  hi = f2bf(x);
  lo = f2bf(x - b2f(hi));
}
DEVI unsigned short f2bf_lo(float x, unsigned short hi){
  return f2bf(x - b2f(hi));
}

DEVI float dotg(const unsigned short* wb, const float4* xr, int i8, float acc){
  us8 w = ((const us8*)wb)[i8];
  float4 xa = xr[2*i8], xb = xr[2*i8+1];
  acc += b2f(w[0])*xa.x; acc += b2f(w[1])*xa.y; acc += b2f(w[2])*xa.z; acc += b2f(w[3])*xa.w;
  acc += b2f(w[4])*xb.x; acc += b2f(w[5])*xb.y; acc += b2f(w[6])*xb.z; acc += b2f(w[7])*xb.w;
  return acc;
}
DEVI float dotg(const float* wb, const float4* xr, int i8, float acc){
  float4 wa = ((const float4*)wb)[2*i8], wv = ((const float4*)wb)[2*i8+1];
  float4 xa = xr[2*i8], xb = xr[2*i8+1];
  acc += wa.x*xa.x; acc += wa.y*xa.y; acc += wa.z*xa.z; acc += wa.w*xa.w;
  acc += wv.x*xb.x; acc += wv.y*xb.y; acc += wv.z*xb.z; acc += wv.w*xb.w;
  return acc;
}
template<typename WT>
DEVI float kdot1024(const WT* wbase, const float4* xr){
  float a0=0,a1=0,a2=0,a3=0;
#pragma unroll 4
  for (int it = 0; it < 32; ++it){
    a0 = dotg(wbase, xr, it*4+0, a0);
    a1 = dotg(wbase, xr, it*4+1, a1);
    a2 = dotg(wbase, xr, it*4+2, a2);
    a3 = dotg(wbase, xr, it*4+3, a3);
  }
  return (a0+a1)+(a2+a3);
}

// ---------------- prologue utility kernels ----------------

__global__ void zero2_k(float* __restrict__ a, float* __restrict__ b, int n){
  int i = blockIdx.x*256 + threadIdx.x;
  if (i < n){ a[i] = 0.f; b[i] = 0.f; }
}

__global__ void gather_k(const float* __restrict__ emb, const int* __restrict__ topic,
                         const int* __restrict__ essay, const int* __restrict__ mems,
                         float* __restrict__ xtop, float* __restrict__ embs,
                         float* __restrict__ Mraw,
                         unsigned short* __restrict__ Mhi, unsigned short* __restrict__ Mlo)
{
  int r = blockIdx.x, tid = threadIdx.x;
  int idx; float* dst; size_t boff = 0; bool wb = false;
  if (r < 128){ int tt = r>>4, b = r&15; idx = topic[b*8+tt]; dst = xtop + (size_t)r*512; }
  else if (r < 1168){ int rr = r-128; int s = rr>>4, b = rr&15; int col = s < 64 ? s : 63;
                      idx = essay[b*64+col]; dst = embs + (size_t)rr*512; }
  else { int rr = r-1168; idx = mems[rr]; dst = Mraw + (size_t)rr*512;
         boff = (size_t)rr*512; wb = (Mhi != nullptr); }
  const float4* s4 = (const float4*)(emb + (size_t)idx*512);
  float4 v = s4[tid];
  ((float4*)dst)[tid] = v;
  if (wb){
    ushort4 h, l;
    f2bf2(v.x, h.x, l.x); f2bf2(v.y, h.y, l.y);
    f2bf2(v.z, h.z, l.z); f2bf2(v.w, h.w, l.w);
    ((ushort4*)(Mhi+boff))[tid] = h;
    ((ushort4*)(Mlo+boff))[tid] = l;
  }
}

// tier0/2: UcatI fp32 interleaved + Ws3T fp32
__global__ void pack_k(const float* __restrict__ U1, const float* __restrict__ U2,
                       const float* __restrict__ sharpW,
                       float* __restrict__ UcatI, float* __restrict__ Ws3T)
{
  int gid = blockIdx.x*256 + threadIdx.x;
  if (gid < 524288){
    int n = gid>>9, k = gid&511;
    UcatI[gid] = (n&1) ? U2[(size_t)(n>>1)*512+k] : U1[(size_t)(n>>1)*512+k];
  } else {
    int g2 = gid - 524288;
    int k = g2>>10, j = g2&1023;
    Ws3T[g2] = sharpW[(size_t)j*2048 + 1536 + k];
  }
}

__global__ void pack_u_hilo(const float* __restrict__ U1, const float* __restrict__ U2,
                            unsigned short* __restrict__ Uhi, unsigned short* __restrict__ Ulo)
{
  int gid = blockIdx.x*256 + threadIdx.x;
  int n = gid>>9, k = gid&511;
  float v = (n&1) ? U2[(size_t)(n>>1)*512+k] : U1[(size_t)(n>>1)*512+k];
  unsigned short h, l;
  f2bf2(v, h, l);
  Uhi[gid] = h; Ulo[gid] = l;
}

// tier3: Ws3 (sharp_W cols 1536..2047) row-major [1024 j][512 k] -> hi/lo
__global__ void pack_ws3b(const float* __restrict__ sharpW,
                          unsigned short* __restrict__ hi, unsigned short* __restrict__ lo)
{
  int gid = blockIdx.x*256 + threadIdx.x;   // 524288
  int j = gid>>9, k = gid&511;
  float v = sharpW[(size_t)j*2048 + 1536 + k];
  unsigned short h, l;
  f2bf2(v, h, l);
  hi[gid] = h; lo[gid] = l;
}

__global__ void conv_k(const float* __restrict__ src, unsigned short* __restrict__ dst, int n8){
  int i = blockIdx.x*256 + threadIdx.x;
  if (i >= n8) return;
  float4 a = ((const float4*)src)[2*i], b = ((const float4*)src)[2*i+1];
  us8 o;
  o[0]=f2bf(a.x); o[1]=f2bf(a.y); o[2]=f2bf(a.z); o[3]=f2bf(a.w);
  o[4]=f2bf(b.x); o[5]=f2bf(b.y); o[6]=f2bf(b.z); o[7]=f2bf(b.w);
  ((us8*)dst)[i] = o;
}

__global__ void conv2_k(const float* __restrict__ src,
                        unsigned short* __restrict__ hi, unsigned short* __restrict__ lo, int n8){
  int i = blockIdx.x*256 + threadIdx.x;
  if (i >= n8) return;
  float4 a = ((const float4*)src)[2*i], b = ((const float4*)src)[2*i+1];
  us8 oh, ol;
  oh[0]=f2bf(a.x); ol[0]=f2bf_lo(a.x, oh[0]);
  oh[1]=f2bf(a.y); ol[1]=f2bf_lo(a.y, oh[1]);
  oh[2]=f2bf(a.z); ol[2]=f2bf_lo(a.z, oh[2]);
  oh[3]=f2bf(a.w); ol[3]=f2bf_lo(a.w, oh[3]);
  oh[4]=f2bf(b.x); ol[4]=f2bf_lo(b.x, oh[4]);
  oh[5]=f2bf(b.y); ol[5]=f2bf_lo(b.y, oh[5]);
  oh[6]=f2bf(b.z); ol[6]=f2bf_lo(b.z, oh[6]);
  oh[7]=f2bf(b.w); ol[7]=f2bf_lo(b.w, oh[7]);
  ((us8*)hi)[i] = oh;
  ((us8*)lo)[i] = ol;
}

// ---------------- generic fp32 tiled GEMM (prologue only) ----------------
template<int ACT>
__global__ void gemm_nt(const float* __restrict__ A, int lda,
                        const float* __restrict__ W, int ldw, int woff,
                        const float* __restrict__ bias,
                        float* __restrict__ C, int ldc, int M, int N, int K)
{
  __shared__ float As[1024], Ws[1024];
  const int bm = blockIdx.y*64, bn = blockIdx.x*64;
  const int tid = threadIdx.x;
  const int lr = tid>>2, lk = (tid&3)<<2;
  const int tm = (tid>>4)<<2, tn = (tid&15)<<2;
  float acc[4][4] = {};
  for (int k0 = 0; k0 < K; k0 += 16){
    float4 av = make_float4(0.f,0.f,0.f,0.f);
    if (bm+lr < M) av = *(const float4*)(A + (size_t)(bm+lr)*lda + k0 + lk);
    As[(lk+0)*64+lr]=av.x; As[(lk+1)*64+lr]=av.y; As[(lk+2)*64+lr]=av.z; As[(lk+3)*64+lr]=av.w;
    float4 wv = make_float4(0.f,0.f,0.f,0.f);
    if (bn+lr < N) wv = *(const float4*)(W + (size_t)(bn+lr)*ldw + woff + k0 + lk);
    Ws[(lk+0)*64+lr]=wv.x; Ws[(lk+1)*64+lr]=wv.y; Ws[(lk+2)*64+lr]=wv.z; Ws[(lk+3)*64+lr]=wv.w;
    __syncthreads();
#pragma unroll
    for (int k = 0; k < 16; ++k){
      float4 a = *(const float4*)&As[k*64+tm];
      float4 w = *(const float4*)&Ws[k*64+tn];
      acc[0][0]+=a.x*w.x; acc[0][1]+=a.x*w.y; acc[0][2]+=a.x*w.z; acc[0][3]+=a.x*w.w;
      acc[1][0]+=a.y*w.x; acc[1][1]+=a.y*w.y; acc[1][2]+=a.y*w.z; acc[1][3]+=a.y*w.w;
      acc[2][0]+=a.z*w.x; acc[2][1]+=a.z*w.y; acc[2][2]+=a.z*w.z; acc[2][3]+=a.z*w.w;
      acc[3][0]+=a.w*w.x; acc[3][1]+=a.w*w.y; acc[3][2]+=a.w*w.z; acc[3][3]+=a.w*w.w;
    }
    __syncthreads();
  }
#pragma unroll
  for (int i = 0; i < 4; ++i){
    int m = bm+tm+i; if (m >= M) continue;
#pragma unroll
    for (int j = 0; j < 4; ++j){
      int n = bn+tn+j; if (n >= N) continue;
      float v = acc[i][j] + (bias ? bias[n] : 0.f);
      if (ACT == 1) v = tanhf(v);
      C[(size_t)m*ldc + n] = v;
    }
  }
}

// ---------------- encoder LSTM step (fp32, 4 waves) ----------------
__global__ void enc_step(const float* __restrict__ xtop,
    const float* __restrict__ Wih_f, const float* __restrict__ Whh_f,
    const float* __restrict__ bih_f, const float* __restrict__ bhh_f,
    const float* __restrict__ Wih_b, const float* __restrict__ Whh_b,
    const float* __restrict__ bih_b, const float* __restrict__ bhh_b,
    const float* __restrict__ h_in, const float* __restrict__ c_in,
    float* __restrict__ h_out, float* __restrict__ c_out,
    float* __restrict__ topics, int t)
{
  const int dir = blockIdx.y;
  const int j = blockIdx.x*4 + (threadIdx.x>>6);
  const int lane = threadIdx.x & 63;
  const int b = lane & 15, g4 = lane >> 4;
  const int tt = dir ? (7 - t) : t;
  const float* Wih = dir ? Wih_b : Wih_f;
  const float* Whh = dir ? Whh_b : Whh_f;
  const float* bih = dir ? bih_b : bih_f;
  const float* bhh = dir ? bhh_b : bhh_f;
  const int row = g4*512 + j;
  float acc = bih[row] + bhh[row];
  const float4* wx = (const float4*)(Wih + (size_t)row*512);
  const float4* xv = (const float4*)(xtop + (size_t)(tt*16+b)*512);
#pragma unroll 8
  for (int k = 0; k < 128; ++k) acc += dot4_(wx[k], xv[k]);
  const float4* wh = (const float4*)(Whh + (size_t)row*512);
  const float4* hv = (const float4*)(h_in + (size_t)b*1024 + dir*512);
#pragma unroll 8
  for (int k = 0; k < 128; ++k) acc += dot4_(wh[k], hv[k]);
  float gi = __shfl(acc, b);
  float gf = __shfl(acc, b+16);
  float gg = __shfl(acc, b+32);
  float go = __shfl(acc, b+48);
  if (g4 == 0){
    float c_old = c_in[(size_t)b*1024 + dir*512 + j];
    float cn = sigmf_(gf)*c_old + sigmf_(gi)*tanhf(gg);
    float hn = sigmf_(go)*tanhf(cn);
    h_out[(size_t)b*1024 + dir*512 + j] = hn;
    c_out[(size_t)b*1024 + dir*512 + j] = cn;
    topics[(size_t)(b*8+tt)*1024 + dir*512 + j] = hn;
  }
}

// ---------------- memory-update GEMM, tier0/2 fp32 ----------------
DEVI void mem_gemm_role(int bid, const float* __restrict__ Min, float* __restrict__ Mout,
                        const float* __restrict__ U,
                        const float* __restrict__ eV1s, const float* __restrict__ eV2s,
                        float* lds, int tid)
{
  const int bm = (bid>>4)*64, bn = (bid&15)*64;
  float* As = lds; float* Ws = lds + 1024;
  const int lr = tid>>2, lk = (tid&3)<<2;
  const int tm = (tid>>4)<<2, tn = (tid&15)<<2;
  float acc[4][4] = {};
  for (int k0 = 0; k0 < 512; k0 += 16){
    float4 av = *(const float4*)(Min + (size_t)(bm+lr)*512 + k0 + lk);
    As[(lk+0)*64+lr]=av.x; As[(lk+1)*64+lr]=av.y; As[(lk+2)*64+lr]=av.z; As[(lk+3)*64+lr]=av.w;
    float4 wv = *(const float4*)(U + (size_t)(bn+lr)*512 + k0 + lk);
    Ws[(lk+0)*64+lr]=wv.x; Ws[(lk+1)*64+lr]=wv.y; Ws[(lk+2)*64+lr]=wv.z; Ws[(lk+3)*64+lr]=wv.w;
    __syncthreads();
#pragma unroll
    for (int k = 0; k < 16; ++k){
      float4 a = *(const float4*)&As[k*64+tm];
      float4 w = *(const float4*)&Ws[k*64+tn];
      acc[0][0]+=a.x*w.x; acc[0][1]+=a.x*w.y; acc[0][2]+=a.x*w.z; acc[0][3]+=a.x*w.w;
      acc[1][0]+=a.y*w.x; acc[1][1]+=a.y*w.y; acc[1][2]+=a.y*w.z; acc[1][3]+=a.y*w.w;
      acc[2][0]+=a.z*w.x; acc[2][1]+=a.z*w.y; acc[2][2]+=a.z*w.z; acc[2][3]+=a.z*w.w;
      acc[3][0]+=a.w*w.x; acc[3][1]+=a.w*w.y; acc[3][2]+=a.w*w.z; acc[3][3]+=a.w*w.w;
    }
    __syncthreads();
  }
  const int e0 = (bn+tn)>>1;
#pragma unroll
  for (int i = 0; i < 4; ++i){
    int r = bm+tm+i;
    int b = r/100;
#pragma unroll
    for (int p = 0; p < 2; ++p){
      int e = e0 + p;
      float oldv = Min[(size_t)r*512 + e];
      float mt = tanhf (acc[i][2*p]   + eV1s[(size_t)b*512 + e]);
      float g  = sigmf_(acc[i][2*p+1] + eV2s[(size_t)b*512 + e]);
      float mn = g*mt + (1.f-g)*oldv;
      if (!isfinite(mn)) mn = 1e-31f;
      Mout[(size_t)r*512 + e] = mn;
    }
  }
}

__global__ void mem_update_k(const float* __restrict__ Min, float* __restrict__ Mout,
                             const float* __restrict__ U,
                             const float* __restrict__ eV1s, const float* __restrict__ eV2s)
{
  __shared__ float lds[2080];
  mem_gemm_role(blockIdx.x, Min, Mout, U, eV1s, eV2s, lds, threadIdx.x);
}

// ---------------- memory-update GEMM, tier3: bf16 hi/lo MFMA ----------------
DEVI void mem_ep(f32x4 v, int m0, int n0, int i, int j, int kg, int r16, int lane,
                 const float* __restrict__ Min,
                 const float* __restrict__ eV1s, const float* __restrict__ eV2s,
                 float* __restrict__ Mout,
                 unsigned short* __restrict__ Mohi, unsigned short* __restrict__ Molo)
{
#pragma unroll
  for (int q = 0; q < 4; ++q){
    float val = v[q];
    float oth = __shfl_xor(val, 1);
    if (!(lane&1)){
      int m = m0 + i*16 + kg*4 + q;
      int n = n0 + j*16 + r16;
      int e = n>>1, bb = m/100;
      float mold = Min[(size_t)m*512 + e];
      float mt = tanhf (val + eV1s[(size_t)bb*512 + e]);
      float g  = sigmf_(oth + eV2s[(size_t)bb*512 + e]);
      float mn = g*mt + (1.f-g)*mold;
      if (!isfinite(mn)) mn = 1e-31f;
      Mout[(size_t)m*512 + e] = mn;
      unsigned short h, l;
      f2bf2(mn, h, l);
      Mohi[(size_t)m*512 + e] = h;
      Molo[(size_t)m*512 + e] = l;
    }
  }
}

// 1600 blocks, 32x32 tile/block, 4 waves split K, LDS reduce. XCD m-chunk swizzle inside.
DEVI void mem_mfma_role2(int hwbid, const float* __restrict__ Min,
                        const unsigned short* __restrict__ Mhi, const unsigned short* __restrict__ Mlo,
                        float* __restrict__ Mout,
                        unsigned short* __restrict__ Mohi, unsigned short* __restrict__ Molo,
                        const unsigned short* __restrict__ Uhi, const unsigned short* __restrict__ Ulo,
                        const float* __restrict__ eV1s, const float* __restrict__ eV2s,
                        int tid, float* __restrict__ lds)
{
  const int bid2 = (hwbid & 7)*200 + (hwbid >> 3);
  const int bm = (bid2 >> 5)*32, bn = (bid2 & 31)*32;
  const int wave = tid>>6, lane = tid&63;
  const int r16 = lane&15, kg = lane>>4;
  const size_t aoff = (size_t)(bm + r16)*512 + wave*128 + kg*8;
  const size_t boff = (size_t)(bn + r16)*512 + wave*128 + kg*8;
  const unsigned short* pa0h = Mhi + aoff; const unsigned short* pa0l = Mlo + aoff;
  const unsigned short* pb0h = Uhi + boff; const unsigned short* pb0l = Ulo + boff;
  f32x4 c00 = {}, c01 = {}, c10 = {}, c11 = {};
#pragma unroll
  for (int k0 = 0; k0 < 128; k0 += 32){
    bfv a0h = *(const bfv*)(pa0h + k0);
    bfv a0l = *(const bfv*)(pa0l + k0);
    bfv a1h = *(const bfv*)(pa0h + 16*512 + k0);
    bfv a1l = *(const bfv*)(pa0l + 16*512 + k0);
    bfv b0h = *(const bfv*)(pb0h + k0);
    bfv b0l = *(const bfv*)(pb0l + k0);
    bfv b1h = *(const bfv*)(pb0h + 16*512 + k0);
    bfv b1l = *(const bfv*)(pb0l + 16*512 + k0);
    c00 = __builtin_amdgcn_mfma_f32_16x16x32_bf16(a0h, b0h, c00, 0, 0, 0);
    c00 = __builtin_amdgcn_mfma_f32_16x16x32_bf16(a0h, b0l, c00, 0, 0, 0);
    c00 = __builtin_amdgcn_mfma_f32_16x16x32_bf16(a0l, b0h, c00, 0, 0, 0);
    c01 = __builtin_amdgcn_mfma_f32_16x16x32_bf16(a0h, b1h, c01, 0, 0, 0);
    c01 = __builtin_amdgcn_mfma_f32_16x16x32_bf16(a0h, b1l, c01, 0, 0, 0);
    c01 = __builtin_amdgcn_mfma_f32_16x16x32_bf16(a0l, b1h, c01, 0, 0, 0);
    c10 = __builtin_amdgcn_mfma_f32_16x16x32_bf16(a1h, b0h, c10, 0, 0, 0);
    c10 = __builtin_amdgcn_mfma_f32_16x16x32_bf16(a1h, b0l, c10, 0, 0, 0);
    c10 = __builtin_amdgcn_mfma_f32_16x16x32_bf16(a1l, b0h, c10, 0, 0, 0);
    c11 = __builtin_amdgcn_mfma_f32_16x16x32_bf16(a1h, b1h, c11, 0, 0, 0);
    c11 = __builtin_amdgcn_mfma_f32_16x16x32_bf16(a1h, b1l, c11, 0, 0, 0);
    c11 = __builtin_amdgcn_mfma_f32_16x16x32_bf16(a1l, b1h, c11, 0, 0, 0);
  }
  float* wbase = lds + wave*1024 + lane*4;
#pragma unroll
  for (int q = 0; q < 4; ++q){
    wbase[q]     = c00[q];
    wbase[256+q] = c01[q];
    wbase[512+q] = c10[q];
    wbase[768+q] = c11[q];
  }
  __syncthreads();
  f32x4 s;
#pragma unroll
  for (int q = 0; q < 4; ++q)
    s[q] = lds[       wave*256 + lane*4 + q] + lds[1024 + wave*256 + lane*4 + q]
         + lds[2048 + wave*256 + lane*4 + q] + lds[3072 + wave*256 + lane*4 + q];
  mem_ep(s, bm, bn, wave>>1, wave&1, kg, r16, lane, Min, eV1s, eV2s, Mout, Mohi, Molo);
}

__global__ __launch_bounds__(256,4) void mem_update_k2(
    const float* __restrict__ Min,
    const unsigned short* __restrict__ Mhi, const unsigned short* __restrict__ Mlo,
    float* __restrict__ Mout,
    unsigned short* __restrict__ Mohi, unsigned short* __restrict__ Molo,
    const unsigned short* __restrict__ Uhi, const unsigned short* __restrict__ Ulo,
    const float* __restrict__ eV1s, const float* __restrict__ eV2s)
{
  __shared__ float lds[4096];
  mem_mfma_role2(blockIdx.x, Min, Mhi, Mlo, Mout, Mohi, Molo, Uhi, Ulo, eV1s, eV2s, threadIdx.x, lds);
}

// ---------------- logits role (shared by attn_mega and logits_k) ----------------
DEVI void logits_role(int lb, int tid,
    const unsigned short* __restrict__ fcWb, const float* __restrict__ fcb,
    const unsigned short* __restrict__ hh, const unsigned short* __restrict__ hl,
    float* __restrict__ out, int t)
{
  const int wave = tid>>6, lane = tid&63;
  const int r16 = lane&15, kg = lane>>4;
  const int tile = lb*4 + wave;   // 0..1999
  const unsigned short* pa0 = fcWb + (size_t)(tile*16 + r16)*1024 + kg*8;
  const unsigned short* pbh = hh + (size_t)r16*1024 + kg*8;
  const unsigned short* pbl = hl + (size_t)r16*1024 + kg*8;
  f32x4 c0 = {};
#pragma unroll 4
  for (int k0 = 0; k0 < 1024; k0 += 32){
    bfv a0 = *(const bfv*)(pa0 + k0);
    bfv b0 = *(const bfv*)(pbh + k0);
    bfv b1 = *(const bfv*)(pbl + k0);
    c0 = __builtin_amdgcn_mfma_f32_16x16x32_bf16(a0, b0, c0, 0,0,0);
    c0 = __builtin_amdgcn_mfma_f32_16x16x32_bf16(a0, b1, c0, 0,0,0);
  }
  float* ob = out + (size_t)r16*2048000 + (size_t)t*32000;
#pragma unroll
  for (int q = 0; q < 4; ++q){
    int j0 = tile*16 + kg*4 + q;
    ob[j0] = c0[q] + fcb[j0];
  }
}

__global__ __launch_bounds__(256) void logits_k(
    const unsigned short* __restrict__ fcWb, const float* __restrict__ fcb,
    const unsigned short* __restrict__ hh, const unsigned short* __restrict__ hl,
    float* __restrict__ out, int t)
{
  logits_role(blockIdx.x, threadIdx.x, fcWb, fcb, hh, hl, out, t);
}

// ---------------- per-step kernel A, tier0/2 (fp32, includes xs) ----------------
__global__ void step_pre(const float* __restrict__ Min, float* __restrict__ Mout,
    const float* __restrict__ U,
    const float* __restrict__ eV1s, const float* __restrict__ eV2s,
    const float* __restrict__ qb, const float* __restrict__ vb,
    const float* __restrict__ pret, const float* __restrict__ tws2,
    const float* __restrict__ eWs1t, const float* __restrict__ sharp_b,
    const float* __restrict__ Ws3T, float* __restrict__ xs)
{
  __shared__ float lds[2080];
  const int tid = threadIdx.x;
  if (blockIdx.x >= 16){
    mem_gemm_role(blockIdx.x-16, Min, Mout, U, eV1s, eV2s, lds, tid);
    return;
  }
  const int b = blockIdx.x;
  lds[tid]         = qb[b*512 + tid];
  lds[tid+256]     = qb[b*512 + tid + 256];
  lds[512+tid]     = vb[b*512 + tid];
  lds[512+tid+256] = vb[b*512 + tid + 256];
  __syncthreads();
  {
    const int tq = tid>>5, l32 = tid&31;
    const float* pr = pret + (size_t)(b*8+tq)*512;
    float sv = 0.f;
#pragma unroll
    for (int i = 0; i < 16; ++i){ int a = l32 + 32*i; sv += pr[a]*lds[a]; }
#pragma unroll
    for (int m = 16; m; m >>= 1) sv += __shfl_xor(sv, m);
    if (l32 == 0) lds[1024+tq] = sv;
  }
  __syncthreads();
  {
    float mx = -1e30f;
#pragma unroll
    for (int i = 0; i < 8; ++i) mx = fmaxf(mx, lds[1024+i]);
    float sm = 0.f; float ev[8];
#pragma unroll
    for (int i = 0; i < 8; ++i){ ev[i] = expf(lds[1024+i]-mx); sm += ev[i]; }
    if (tid < 8) lds[1032+tid] = ev[tid]/sm;
  }
  __syncthreads();
  {
    const int wv = tid>>6, lane = tid&63;
    for (int l = wv; l < 100; l += 4){
      const float* Mr = Min + (size_t)(b*100+l)*512;
      float sv = 0.f;
#pragma unroll
      for (int i = 0; i < 8; ++i){ int k = lane + 64*i; sv += Mr[k]*lds[512+k]; }
      sv = wred64(sv);
      if (lane == 0) lds[1040+l] = sv;
    }
  }
  __syncthreads();
  float mx = -1e30f;
  for (int i = 0; i < 100; ++i) mx = fmaxf(mx, lds[1040+i]);
  __syncthreads();
  if (tid < 100) lds[1040+tid] = expf(lds[1040+tid]-mx);
  __syncthreads();
  float sm = 0.f;
  for (int i = 0; i < 100; ++i) sm += lds[1040+i];
  const float inv = 1.f/sm;
  for (int e = tid; e < 512; e += 256){
    float a = 0.f;
    for (int l = 0; l < 100; ++l) a += lds[1040+l]*Min[(size_t)(b*100+l)*512 + e];
    lds[1152+e] = a*inv;
  }
  __syncthreads();
  float a0[4];
#pragma unroll
  for (int r2 = 0; r2 < 4; ++r2){
    int j = tid + 256*r2;
    float v = sharp_b[j] + eWs1t[(size_t)b*1024 + j];
#pragma unroll
    for (int t2 = 0; t2 < 8; ++t2) v += lds[1032+t2]*tws2[(size_t)(b*8+t2)*1024 + j];
    a0[r2] = v;
  }
  for (int k = 0; k < 512; ++k){
    float mk = lds[1152+k];
    const float* wr = Ws3T + (size_t)k*1024;
    a0[0] += mk*wr[tid];
    a0[1] += mk*wr[tid+256];
    a0[2] += mk*wr[tid+512];
    a0[3] += mk*wr[tid+768];
  }
#pragma unroll
  for (int r2 = 0; r2 < 4; ++r2) xs[(size_t)b*1024 + tid + 256*r2] = a0[r2];
}

// ---------------- per-step mega kernel, tier3: mt (128) + logits(t-1) (nLog) + mem GEMM (1600) ----------------
__global__ __launch_bounds__(256,4) void attn_mega(
    const float* __restrict__ Min,
    const unsigned short* __restrict__ Mhi, const unsigned short* __restrict__ Mlo,
    float* __restrict__ Mout,
    unsigned short* __restrict__ Mohi, unsigned short* __restrict__ Molo,
    const unsigned short* __restrict__ Uhi, const unsigned short* __restrict__ Ulo,
    const float* __restrict__ eV1s, const float* __restrict__ eV2s,
    const float* __restrict__ qb, const float* __restrict__ vb,
    const float* __restrict__ pret,
    float* __restrict__ alphab,
    unsigned short* __restrict__ mthi, unsigned short* __restrict__ mtlo,
    const unsigned short* __restrict__ fcWb, const float* __restrict__ fcb,
    const unsigned short* __restrict__ hph, const unsigned short* __restrict__ hpl,
    float* __restrict__ out, int tlog, int nLog)
{
  __shared__ float lds[4096];
  const int tid = threadIdx.x;
  if (blockIdx.x >= 128){
    const int bid = blockIdx.x - 128;
    if (bid < nLog){
      logits_role(bid, tid, fcWb, fcb, hph, hpl, out, tlog);
      return;
    }
    mem_mfma_role2(bid - nLog, Min, Mhi, Mlo, Mout, Mohi, Molo, Uhi, Ulo, eV1s, eV2s, tid, lds);
    return;
  }
  const int b = blockIdx.x >> 3, ec = blockIdx.x & 7;
  lds[tid]         = qb[b*512 + tid];
  lds[tid+256]     = qb[b*512 + tid + 256];
  lds[512+tid]     = vb[b*512 + tid];
  lds[512+tid+256] = vb[b*512 + tid + 256];
  __syncthreads();
  // topic scores + softmax-8 + alpha (ec==0 blocks only)
  if (ec == 0){
    {
      const int tq = tid>>5, l32 = tid&31;
      const float* pr = pret + (size_t)(b*8+tq)*512;
      float sv = 0.f;
#pragma unroll
      for (int i = 0; i < 16; ++i){ int a = l32 + 32*i; sv += pr[a]*lds[a]; }
#pragma unroll
      for (int m = 16; m; m >>= 1) sv += __shfl_xor(sv, m);
      if (l32 == 0) lds[1024+tq] = sv;
    }
    __syncthreads();
    {
      float mx = -1e30f;
#pragma unroll
      for (int i = 0; i < 8; ++i) mx = fmaxf(mx, lds[1024+i]);
      float sm = 0.f; float ev[8];
#pragma unroll
      for (int i = 0; i < 8; ++i){ ev[i] = expf(lds[1024+i]-mx); sm += ev[i]; }
      if (tid < 8) alphab[b*8+tid] = ev[tid]/sm;
    }
    __syncthreads();
  }
  // memory scores (100)
  {
    const int wv = tid>>6, lane = tid&63;
    for (int l = wv; l < 100; l += 4){
      const float* Mr = Min + (size_t)(b*100+l)*512;
      float sv = 0.f;
#pragma unroll
      for (int i = 0; i < 8; ++i){ int k = lane + 64*i; sv += Mr[k]*lds[512+k]; }
      sv = wred64(sv);
      if (lane == 0) lds[1040+l] = sv;
    }
  }
  __syncthreads();
  // parallel softmax over 100 -> normalized weights in LDS
  {
    const int wv = tid>>6;
    float v100 = (tid < 100) ? lds[1040+tid] : -1e30f;
    float m1 = v100;
#pragma unroll
    for (int m = 32; m; m >>= 1) m1 = fmaxf(m1, __shfl_xor(m1, m));
    if ((tid&63) == 0) lds[1664+wv] = m1;
    __syncthreads();
    float mx = fmaxf(fmaxf(lds[1664], lds[1665]), fmaxf(lds[1666], lds[1667]));
    float e = (tid < 100) ? expf(v100 - mx) : 0.f;
    float s1 = e;
#pragma unroll
    for (int m = 32; m; m >>= 1) s1 += __shfl_xor(s1, m);
    if ((tid&63) == 0) lds[1668+wv] = s1;
    __syncthreads();
    float sm = lds[1668]+lds[1669]+lds[1670]+lds[1671];
    if (tid < 100) lds[1800+tid] = e/sm;
  }
  __syncthreads();
  // m_t for e-chunk ec
  {
    const int e = ec*64 + (tid & 63);
    const int lg = tid >> 6;
    float a = 0.f;
    for (int l = lg*25; l < lg*25 + 25; ++l)
      a += lds[1800+l] * Min[(size_t)(b*100 + l)*512 + e];
    lds[1904 + lg*64 + (tid & 63)] = a;
    __syncthreads();
    if (lg == 0){
      float s = lds[1904 + tid] + lds[1968 + tid] + lds[2032 + tid] + lds[2096 + tid];
      unsigned short h, l2;
      f2bf2(s, h, l2);
      mthi[b*512 + e] = h;
      mtlo[b*512 + e] = l2;
    }
  }
}

// ---------------- per-step kernel A2, tier3: xs via hi/lo MFMA (64 blocks) ----------------
__global__ __launch_bounds__(256) void xs_k(
    const unsigned short* __restrict__ Ws3hi, const unsigned short* __restrict__ Ws3lo,
    const unsigned short* __restrict__ mthi, const unsigned short* __restrict__ mtlo,
    const float* __restrict__ alphab, const float* __restrict__ sharp_b,
    const float* __restrict__ eWs1t, const float* __restrict__ tws2,
    unsigned short* __restrict__ xshi, unsigned short* __restrict__ xslo)
{
  __shared__ float lds[1024];
  const int tid = threadIdx.x, wave = tid>>6, lane = tid&63;
  const int r16 = lane&15, kg = lane>>4;
  const int jt = blockIdx.x;    // 0..63
  const size_t aoff = (size_t)(jt*16 + r16)*512 + wave*128 + kg*8;
  const size_t boff = (size_t)r16*512 + wave*128 + kg*8;
  f32x4 c0 = {};
#pragma unroll
  for (int k0 = 0; k0 < 128; k0 += 32){
    bfv ah = *(const bfv*)(Ws3hi + aoff + k0);
    bfv al = *(const bfv*)(Ws3lo + aoff + k0);
    bfv bh = *(const bfv*)(mthi + boff + k0);
    bfv bl = *(const bfv*)(mtlo + boff + k0);
    c0 = __builtin_amdgcn_mfma_f32_16x16x32_bf16(ah, bh, c0, 0,0,0);
    c0 = __builtin_amdgcn_mfma_f32_16x16x32_bf16(ah, bl, c0, 0,0,0);
    c0 = __builtin_amdgcn_mfma_f32_16x16x32_bf16(al, bh, c0, 0,0,0);
  }
  float* wb2 = lds + wave*256 + lane*4;
#pragma unroll
  for (int q = 0; q < 4; ++q) wb2[q] = c0[q];
  __syncthreads();
  if (wave == 0){
    const int b = r16;
#pragma unroll
    for (int q = 0; q < 4; ++q){
      float s = lds[lane*4+q] + lds[256+lane*4+q] + lds[512+lane*4+q] + lds[768+lane*4+q];
      int j = jt*16 + kg*4 + q;
      float v2 = s + sharp_b[j] + eWs1t[(size_t)b*1024 + j];
#pragma unroll
      for (int t2 = 0; t2 < 8; ++t2) v2 += alphab[b*8+t2]*tws2[(size_t)(b*8+t2)*1024 + j];
      unsigned short h, l;
      f2bf2(v2, h, l);
      xshi[b*1024+j] = h;
      xslo[b*1024+j] = l;
    }
  }
}

// ---------------- per-step kernel B, tier0/2 ----------------
__global__ void dec_lstm(const float* __restrict__ xs,
    const float* __restrict__ Wih, const float* __restrict__ Whh,
    const float* __restrict__ bih, const float* __restrict__ bhh,
    const float* __restrict__ h_in, const float* __restrict__ c_in,
    float* __restrict__ h_out, float* __restrict__ c_out)
{
  const int j = blockIdx.x*4 + (threadIdx.x>>6);
  const int lane = threadIdx.x & 63;
  const int b = lane & 15, g4 = lane >> 4;
  const int row = g4*1024 + j;
  float acc = bih[row] + bhh[row];
  const float4* w1 = (const float4*)(Wih + (size_t)row*1024);
  const float4* x1 = (const float4*)(xs + (size_t)b*1024);
#pragma unroll 8
  for (int k = 0; k < 256; ++k) acc += dot4_(w1[k], x1[k]);
  const float4* w2 = (const float4*)(Whh + (size_t)row*1024);
  const float4* h1 = (const float4*)(h_in + (size_t)b*1024);
#pragma unroll 8
  for (int k = 0; k < 256; ++k) acc += dot4_(w2[k], h1[k]);
  float gi = __shfl(acc, b);
  float gf = __shfl(acc, b+16);
  float gg = __shfl(acc, b+32);
  float go = __shfl(acc, b+48);
  if (g4 == 0){
    float c_old = c_in[(size_t)b*1024 + j];
    float cn = sigmf_(gf)*c_old + sigmf_(gi)*tanhf(gg);
    float hn = sigmf_(go)*tanhf(cn);
    h_out[(size_t)b*1024 + j] = hn;
    c_out[(size_t)b*1024 + j] = cn;
  }
}

// ---------------- per-step kernel B, tier3: MFMA decoder LSTM (64 blocks, 256 thr) ----------------
__global__ __launch_bounds__(256) void dec_mfma(
    const unsigned short* __restrict__ xsh, const unsigned short* __restrict__ xsl,
    const unsigned short* __restrict__ Wih_h, const unsigned short* __restrict__ Wih_l,
    const unsigned short* __restrict__ Whh_h, const unsigned short* __restrict__ Whh_l,
    const float* __restrict__ bih, const float* __restrict__ bhh,
    const unsigned short* __restrict__ hih, const unsigned short* __restrict__ hil,
    const float* __restrict__ c_in,
    float* __restrict__ h_out, float* __restrict__ c_out,
    unsigned short* __restrict__ hoh, unsigned short* __restrict__ hol,
    unsigned short* __restrict__ coh, unsigned short* __restrict__ col_)
{
  __shared__ float acc_lds[4][4][64][4];   // [kh][gate][lane][q]
  __shared__ float gat[4][64][4];          // [gate][lane][q]
  const int tid = threadIdx.x, kh = tid>>6, lane = tid&63;
  const int r16 = lane&15, kg = lane>>4;
  const int jt = blockIdx.x;
  const size_t arow = (size_t)(jt*16 + r16)*1024 + kh*256 + kg*8;   // + g*1048576
  const size_t boff = (size_t)r16*1024 + kh*256 + kg*8;
  f32x4 c0 = {}, c1 = {}, c2 = {}, c3 = {};
#pragma unroll 2
  for (int k0 = 0; k0 < 256; k0 += 32){
    bfv bxh = *(const bfv*)(xsh + boff + k0);
    bfv bxl = *(const bfv*)(xsl + boff + k0);
    bfv bhh_ = *(const bfv*)(hih + boff + k0);
    bfv bhl_ = *(const bfv*)(hil + boff + k0);
#define DEC_GATE(G, CC) { \
    bfv aih = *(const bfv*)(Wih_h + arow + (size_t)(G)*1048576 + k0); \
    bfv ail = *(const bfv*)(Wih_l + arow + (size_t)(G)*1048576 + k0); \
    bfv ahh = *(const bfv*)(Whh_h + arow + (size_t)(G)*1048576 + k0); \
    bfv ahl = *(const bfv*)(Whh_l + arow + (size_t)(G)*1048576 + k0); \
    CC = __builtin_amdgcn_mfma_f32_16x16x32_bf16(aih, bxh, CC, 0,0,0); \
    CC = __builtin_amdgcn_mfma_f32_16x16x32_bf16(aih, bxl, CC, 0,0,0); \
    CC = __builtin_amdgcn_mfma_f32_16x16x32_bf16(ail, bxh, CC, 0,0,0); \
    CC = __builtin_amdgcn_mfma_f32_16x16x32_bf16(ahh, bhh_, CC, 0,0,0); \
    CC = __builtin_amdgcn_mfma_f32_16x16x32_bf16(ahh, bhl_, CC, 0,0,0); \
    CC = __builtin_amdgcn_mfma_f32_16x16x32_bf16(ahl, bhh_, CC, 0,0,0); }
    DEC_GATE(0, c0)
    DEC_GATE(1, c1)
    DEC_GATE(2, c2)
    DEC_GATE(3, c3)
#undef DEC_GATE
  }
#pragma unroll
  for (int q = 0; q < 4; ++q){
    acc_lds[kh][0][lane][q] = c0[q];
    acc_lds[kh][1][lane][q] = c1[q];
    acc_lds[kh][2][lane][q] = c2[q];
    acc_lds[kh][3][lane][q] = c3[q];
  }
  __syncthreads();
  {
    const int g = kh;
#pragma unroll
    for (int q = 0; q < 4; ++q)
      gat[g][lane][q] = acc_lds[0][g][lane][q] + acc_lds[1][g][lane][q]
                      + acc_lds[2][g][lane][q] + acc_lds[3][g][lane][q];
  }
  __syncthreads();
  {
    const int b = tid&15, joff = tid>>4;
    const int l2 = (joff>>2)*16 + b, q2 = joff&3;
    const int j = jt*16 + joff;
    float gi = gat[0][l2][q2] + bih[j]        + bhh[j];
    float gf = gat[1][l2][q2] + bih[1024+j]   + bhh[1024+j];
    float gg = gat[2][l2][q2] + bih[2048+j]   + bhh[2048+j];
    float go = gat[3][l2][q2] + bih[3072+j]   + bhh[3072+j];
    float cold = c_in[b*1024 + j];
    float cn = sigmf_(gf)*cold + sigmf_(gi)*tanhf(gg);
    float hn = sigmf_(go)*tanhf(cn);
    h_out[b*1024 + j] = hn;
    c_out[b*1024 + j] = cn;
    unsigned short uh, ul;
    f2bf2(hn, uh, ul); hoh[b*1024+j] = uh; hol[b*1024+j] = ul;
    f2bf2(cn, uh, ul); coh[b*1024+j] = uh; col_[b*1024+j] = ul;
  }
}

// ---------------- per-step kernel qv, tier3: q and v (64 blocks, K-split 4 + LDS reduce) ----------------
__global__ __launch_bounds__(256) void qv_k(
    const unsigned short* __restrict__ W2h, const unsigned short* __restrict__ W2l,
    const unsigned short* __restrict__ mWh, const unsigned short* __restrict__ mWl,
    const float* __restrict__ memb,
    const unsigned short* __restrict__ hh, const unsigned short* __restrict__ hl,
    const unsigned short* __restrict__ ch, const unsigned short* __restrict__ cl,
    float* __restrict__ qb, float* __restrict__ vb)
{
  __shared__ float lds[1024];
  const int tid = threadIdx.x, wave = tid>>6, lane = tid&63;
  const int r16 = lane&15, kg = lane>>4;
  const bool isV = blockIdx.x >= 32;
  const int tile = isV ? ((int)blockIdx.x - 32) : (int)blockIdx.x;   // 0..31
  const unsigned short* Ah = isV ? mWh : W2h;
  const unsigned short* Al = isV ? mWl : W2l;
  const unsigned short* Bh = isV ? hh : ch;
  const unsigned short* Bl = isV ? hl : cl;
  const size_t aoff = (size_t)(tile*16 + r16)*1024 + wave*256 + kg*8;
  const size_t boff = (size_t)r16*1024 + wave*256 + kg*8;
  f32x4 c0 = {};
#pragma unroll
  for (int k0 = 0; k0 < 256; k0 += 32){
    bfv ah = *(const bfv*)(Ah + aoff + k0);
    bfv al = *(const bfv*)(Al + aoff + k0);
    bfv b0 = *(const bfv*)(Bh + boff + k0);
    bfv b1 = *(const bfv*)(Bl + boff + k0);
    c0 = __builtin_amdgcn_mfma_f32_16x16x32_bf16(ah, b0, c0, 0,0,0);
    c0 = __builtin_amdgcn_mfma_f32_16x16x32_bf16(ah, b1, c0, 0,0,0);
    c0 = __builtin_amdgcn_mfma_f32_16x16x32_bf16(al, b0, c0, 0,0,0);
  }
  float* wb2 = lds + wave*256 + lane*4;
#pragma unroll
  for (int q = 0; q < 4; ++q) wb2[q] = c0[q];
  __syncthreads();
  if (wave == 0){
#pragma unroll
    for (int q = 0; q < 4; ++q){
      float s = lds[lane*4+q] + lds[256+lane*4+q] + lds[512+lane*4+q] + lds[768+lane*4+q];
      int j = tile*16 + kg*4 + q;
      if (isV) vb[r16*512 + j] = tanhf(s + memb[j]);
      else     qb[r16*512 + j] = s;
    }
  }
}

// ---------------- per-step kernel C, tier0/2 ----------------
template<typename WT>
__global__ __launch_bounds__(256,4) void step_out_t(const float* __restrict__ h, const float* __restrict__ c,
    const WT* __restrict__ fcW_, const float* __restrict__ fcb,
    const float* __restrict__ W2, const float* __restrict__ memW,
    const float* __restrict__ memb,
    float* __restrict__ out, float* __restrict__ qb, float* __restrict__ vb, int t)
{
  __shared__ float tile[256];
  const int bid = blockIdx.x;
  const int wv = threadIdx.x>>6, lane = threadIdx.x&63;
  const int b = lane&15, jj = lane>>4;
  if (bid < 2000){
    const int j = bid*16 + wv*4 + jj;
    float acc = kdot1024(fcW_ + (size_t)j*1024, (const float4*)(h + (size_t)b*1024));
    tile[(wv*4+jj)*16 + b] = acc;
    __syncthreads();
    const int b2 = threadIdx.x>>4, j2 = threadIdx.x&15;
    out[(size_t)b2*2048000 + (size_t)t*32000 + bid*16 + j2] = tile[j2*16+b2] + fcb[bid*16+j2];
  } else if (bid < 2032){
    const int j = (bid-2000)*16 + wv*4 + jj;
    float acc = kdot1024(W2 + (size_t)j*1024, (const float4*)(c + (size_t)b*1024));
    qb[b*512 + j] = acc;
  } else {
    const int j = (bid-2032)*16 + wv*4 + jj;
    float acc = kdot1024(memW + (size_t)j*1024, (const float4*)(h + (size_t)b*1024));
    vb[b*512 + j] = tanhf(acc + memb[j]);
  }
}

// ---------------- host launch ----------------
extern "C" void kernel_launch(void* const* d_in, const int* in_sizes, int n_in,
                              void* d_out, int out_size, void* d_ws, size_t ws_size,
                              hipStream_t stream)
{
  const float* embedding = (const float*)d_in[0];
  const float* Wih_f = (const float*)d_in[1];
  const float* Whh_f = (const float*)d_in[2];
  const float* bih_f = (const float*)d_in[3];
  const float* bhh_f = (const float*)d_in[4];
  const float* Wih_b = (const float*)d_in[5];
  const float* Whh_b = (const float*)d_in[6];
  const float* bih_b = (const float*)d_in[7];
  const float* bhh_b = (const float*)d_in[8];
  const float* W1    = (const float*)d_in[9];
  const float* W2    = (const float*)d_in[10];
  const float* mem_W = (const float*)d_in[11];
  const float* mem_b = (const float*)d_in[12];
  const float* U1    = (const float*)d_in[13];
  const float* V1    = (const float*)d_in[14];
  const float* U2    = (const float*)d_in[15];
  const float* V2    = (const float*)d_in[16];
  const float* sharp_W = (const float*)d_in[17];
  const float* sharp_b = (const float*)d_in[18];
  const float* dec_Wih = (const float*)d_in[19];
  const float* dec_Whh = (const float*)d_in[20];
  const float* dec_bih = (const float*)d_in[21];
  const float* dec_bhh = (const float*)d_in[22];
  const float* fc_W  = (const float*)d_in[23];
  const float* fc_b  = (const float*)d_in[24];
  const int* topic   = (const int*)d_in[25];
  const int* essay   = (const int*)d_in[27];
  const int* mems    = (const int*)d_in[29];
  float* out = (float*)d_out;
  float* ws = (float*)d_ws;

  // fp32 region
  float* x_topic = ws;                 // [8][16][512]
  float* embs    = ws + 65536;         // [65][16][512]
  float* eV1     = ws + 598016;        // [65][16][512]
  float* eV2     = ws + 1130496;       // [65][16][512]
  float* eWs1    = ws + 1662976;       // [65][16][1024]
  float* topics  = ws + 2727936;       // [16][8][1024]
  float* tws2    = ws + 2859008;       // [16][8][1024]
  float* pret    = ws + 2990080;       // [16][8][512]
  float* Mb0     = ws + 3055616;       // [1600][512]
  float* Mb1     = ws + 3874816;       // [1600][512]
  float* h_buf   = ws + 4694016;       // [2][16][1024]
  float* c_buf   = ws + 4726784;       // [2][16][1024]
  float* xs      = ws + 4759552;       // [16][1024]
  float* qb      = ws + 4775936;       // [16][512]
  float* vb      = ws + 4784128;       // [16][512]
  float* UcatI   = ws + 4792320;       // [1024][512] fp32 (tier<3)
  float* Ws3T    = ws + 5316608;       // [512][1024] fp32 (tier<3)  end 5840896
  // tier3 aliases inside UcatI/Ws3T slots (mutually exclusive with tier<3 use)
  unsigned short* Ws3hi = (unsigned short*)(ws + 4792320);   // [1024][512] us
  unsigned short* Ws3lo = (unsigned short*)(ws + 5054464);   // [1024][512] us
  unsigned short* mthi  = (unsigned short*)(ws + 5316608);   // [16][512] us
  unsigned short* mtlo  = (unsigned short*)(ws + 5320704);   // [16][512] us
  float*          alphab= ws + 5324800;                      // [16][8] f
  // hi/lo region
  unsigned short* Uhi   = (unsigned short*)(ws + 5840896);
  unsigned short* Ulo   = (unsigned short*)(ws + 6103040);
  unsigned short* Mb0hi = (unsigned short*)(ws + 6365184);
  unsigned short* Mb0lo = (unsigned short*)(ws + 6774784);
  unsigned short* Mb1hi = (unsigned short*)(ws + 7184384);
  unsigned short* Mb1lo = (unsigned short*)(ws + 7593984);   // end 8003584 f
  unsigned short* fcWb  = (unsigned short*)(ws + 8003584);   // end 24387584 f
  // tier3 weights/state
  unsigned short* dWihHi = (unsigned short*)(ws + 24387584);
  unsigned short* dWihLo = (unsigned short*)(ws + 26484736);
  unsigned short* dWhhHi = (unsigned short*)(ws + 28581888);
  unsigned short* dWhhLo = (unsigned short*)(ws + 30679040);
  unsigned short* W2h    = (unsigned short*)(ws + 32776192);
  unsigned short* W2l    = (unsigned short*)(ws + 33038336);
  unsigned short* mWh    = (unsigned short*)(ws + 33300480);
  unsigned short* mWl    = (unsigned short*)(ws + 33562624);
  unsigned short* hbhi   = (unsigned short*)(ws + 33824768);
  unsigned short* hblo   = (unsigned short*)(ws + 33841152);
  unsigned short* cbhi   = (unsigned short*)(ws + 33857536);
  unsigned short* cblo   = (unsigned short*)(ws + 33873920);
  unsigned short* xshi   = (unsigned short*)(ws + 33890304);
  unsigned short* xslo   = (unsigned short*)(ws + 33898496); // end 33906688 f

  const size_t NEED2 = (size_t)24387584 * 4;
  const size_t NEED3 = (size_t)33906688 * 4;   // ~135.6 MB (unchanged)
  const int tier = (ws_size >= NEED3) ? 3 : (ws_size >= NEED2 ? 2 : 0);

  if (tier < 3){
    // -------- proven fp32 path; tier2 uses bf16 fc_W for logits --------
    zero2_k<<<64,256,0,stream>>>(h_buf, c_buf, 16384);
    gather_k<<<2768,128,0,stream>>>(embedding, topic, essay, mems, x_topic, embs, Mb1, nullptr, nullptr);
    pack_k<<<4096,256,0,stream>>>(U1, U2, sharp_W, UcatI, Ws3T);
    if (tier == 2) conv_k<<<16000,256,0,stream>>>(fc_W, fcWb, 4096000);
    gemm_nt<0><<<dim3(8,17),256,0,stream>>>(embs,512, V1,512,0, nullptr, eV1,512, 1040,512,512);
    gemm_nt<0><<<dim3(8,17),256,0,stream>>>(embs,512, V2,512,0, nullptr, eV2,512, 1040,512,512);
    gemm_nt<0><<<dim3(16,17),256,0,stream>>>(embs,512, sharp_W,2048,0, nullptr, eWs1,1024, 1040,1024,512);
    for (int t = 0; t < 8; ++t){
      const float* hi = h_buf + (t&1)*16384;
      const float* ci = c_buf + (t&1)*16384;
      float* ho = h_buf + ((t+1)&1)*16384;
      float* co = c_buf + ((t+1)&1)*16384;
      enc_step<<<dim3(128,2),256,0,stream>>>(x_topic, Wih_f,Whh_f,bih_f,bhh_f,
                                             Wih_b,Whh_b,bih_b,bhh_b, hi,ci,ho,co, topics, t);
    }
    gemm_nt<0><<<dim3(8,2),256,0,stream>>>(topics,1024, W1,1024,0, nullptr, pret,512, 128,512,1024);
    gemm_nt<0><<<dim3(16,2),256,0,stream>>>(topics,1024, sharp_W,2048,512, nullptr, tws2,1024, 128,1024,1024);
    gemm_nt<0><<<dim3(8,1),256,0,stream>>>(c_buf,1024, W2,1024,0, nullptr, qb,512, 16,512,1024);
    gemm_nt<1><<<dim3(8,1),256,0,stream>>>(h_buf,1024, mem_W,1024,0, mem_b, vb,512, 16,512,1024);
    mem_update_k<<<400,256,0,stream>>>(Mb1, Mb0, UcatI, eV1, eV2);
    for (int t = 0; t < 64; ++t){
      float* Mi = (t&1) ? Mb1 : Mb0;
      float* Mo = (t&1) ? Mb0 : Mb1;
      int nb = (t < 63) ? 416 : 16;
      step_pre<<<nb,256,0,stream>>>(Mi, Mo, UcatI,
          eV1 + (size_t)(t+1)*8192, eV2 + (size_t)(t+1)*8192,
          qb, vb, pret, tws2, eWs1 + (size_t)t*16384, sharp_b, Ws3T, xs);
      const float* hi = h_buf + (t&1)*16384;
      const float* ci = c_buf + (t&1)*16384;
      float* ho = h_buf + ((t+1)&1)*16384;
      float* co = c_buf + ((t+1)&1)*16384;
      dec_lstm<<<256,256,0,stream>>>(xs, dec_Wih, dec_Whh, dec_bih, dec_bhh, hi, ci, ho, co);
      if (tier == 2)
        step_out_t<unsigned short><<<2064,256,0,stream>>>(ho, co, fcWb, fc_b, W2, mem_W, mem_b, out, qb, vb, t);
      else
        step_out_t<float><<<2064,256,0,stream>>>(ho, co, fc_W, fc_b, W2, mem_W, mem_b, out, qb, vb, t);
    }
    return;
  }

  // -------- tier3 pipeline --------
  zero2_k<<<64,256,0,stream>>>(h_buf, c_buf, 16384);
  gather_k<<<2768,128,0,stream>>>(embedding, topic, essay, mems, x_topic, embs, Mb1, Mb1hi, Mb1lo);
  pack_u_hilo<<<2048,256,0,stream>>>(U1, U2, Uhi, Ulo);
  pack_ws3b<<<2048,256,0,stream>>>(sharp_W, Ws3hi, Ws3lo);
  conv_k<<<16000,256,0,stream>>>(fc_W, fcWb, 4096000);
  conv2_k<<<2048,256,0,stream>>>(dec_Wih, dWihHi, dWihLo, 524288);
  conv2_k<<<2048,256,0,stream>>>(dec_Whh, dWhhHi, dWhhLo, 524288);
  conv2_k<<<256,256,0,stream>>>(W2, W2h, W2l, 65536);
  conv2_k<<<256,256,0,stream>>>(mem_W, mWh, mWl, 65536);

  gemm_nt<0><<<dim3(8,17),256,0,stream>>>(embs,512, V1,512,0, nullptr, eV1,512, 1040,512,512);
  gemm_nt<0><<<dim3(8,17),256,0,stream>>>(embs,512, V2,512,0, nullptr, eV2,512, 1040,512,512);
  gemm_nt<0><<<dim3(16,17),256,0,stream>>>(embs,512, sharp_W,2048,0, nullptr, eWs1,1024, 1040,1024,512);

  for (int t = 0; t < 8; ++t){
    const float* hi = h_buf + (t&1)*16384;
    const float* ci = c_buf + (t&1)*16384;
    float* ho = h_buf + ((t+1)&1)*16384;
    float* co = c_buf + ((t+1)&1)*16384;
    enc_step<<<dim3(128,2),256,0,stream>>>(x_topic, Wih_f,Whh_f,bih_f,bhh_f,
                                           Wih_b,Whh_b,bih_b,bhh_b, hi,ci,ho,co, topics, t);
  }
  gemm_nt<0><<<dim3(8,2),256,0,stream>>>(topics,1024, W1,1024,0, nullptr, pret,512, 128,512,1024);
  gemm_nt<0><<<dim3(16,2),256,0,stream>>>(topics,1024, sharp_W,2048,512, nullptr, tws2,1024, 128,1024,1024);
  gemm_nt<0><<<dim3(8,1),256,0,stream>>>(c_buf,1024, W2,1024,0, nullptr, qb,512, 16,512,1024);
  gemm_nt<1><<<dim3(8,1),256,0,stream>>>(h_buf,1024, mem_W,1024,0, mem_b, vb,512, 16,512,1024);
  conv2_k<<<8,256,0,stream>>>(h_buf, hbhi, hblo, 2048);   // parity-0 initial state
  conv2_k<<<8,256,0,stream>>>(c_buf, cbhi, cblo, 2048);
  mem_update_k2<<<1600,256,0,stream>>>(Mb1, Mb1hi, Mb1lo, Mb0, Mb0hi, Mb0lo, Uhi, Ulo, eV1, eV2);

  for (int t = 0; t < 64; ++t){
    float* Mi = (t&1) ? Mb1 : Mb0;
    unsigned short* Mihi = (t&1) ? Mb1hi : Mb0hi;
    unsigned short* Milo = (t&1) ? Mb1lo : Mb0lo;
    float* Mo = (t&1) ? Mb0 : Mb1;
    unsigned short* Mohi = (t&1) ? Mb0hi : Mb1hi;
    unsigned short* Molo = (t&1) ? Mb0lo : Mb1lo;
    const int par = t&1, nxt = (t+1)&1;
    const int nLog = (t > 0) ? 500 : 0;
    const int nGemm = (t < 63) ? 1600 : 0;
    // mega-dispatch: mt(t) [128] + logits(t-1) [nLog] + mem GEMM M(t)->M(t+1) [nGemm]
    attn_mega<<<128 + nLog + nGemm,256,0,stream>>>(Mi, Mihi, Milo, Mo, Mohi, Molo, Uhi, Ulo,
        eV1 + (size_t)(t+1)*8192, eV2 + (size_t)(t+1)*8192,
        qb, vb, pret, alphab, mthi, mtlo,
        fcWb, fc_b, hbhi + par*16384, hblo + par*16384, out, t-1, nLog);
    xs_k<<<64,256,0,stream>>>(Ws3hi, Ws3lo, mthi, mtlo, alphab, sharp_b,
        eWs1 + (size_t)t*16384, tws2, xshi, xslo);
    const float* ci = c_buf + par*16384;
    float* ho = h_buf + nxt*16384;
    float* co = c_buf + nxt*16384;
    dec_mfma<<<64,256,0,stream>>>(xshi, xslo, dWihHi, dWihLo, dWhhHi, dWhhLo,
        dec_bih, dec_bhh,
        hbhi + par*16384, hblo + par*16384, ci,
        ho, co,
        hbhi + nxt*16384, hblo + nxt*16384, cbhi + nxt*16384, cblo + nxt*16384);
    if (t < 63)
      qv_k<<<64,256,0,stream>>>(W2h, W2l, mWh, mWl, mem_b,
          hbhi + nxt*16384, hblo + nxt*16384, cbhi + nxt*16384, cblo + nxt*16384, qb, vb);
  }
  // final logits for t=63 (h-state parity 0 after dec(63))
  logits_k<<<500,256,0,stream>>>(fcWb, fc_b, hbhi, hblo, out, 63);
}